// Round 10
// baseline (938.982 us; speedup 1.0000x reference)
//
#include <hip/hip_runtime.h>
#include <stdint.h>

#define N_DET 20000
#define N_CLS 80
#define NELEM (N_DET * N_CLS)
#define TOPK  1000
#define CONF  0.05f
#define CANDS 1280
#define SORTN 2048
#define NBLK  40   // blocks for hist/scatter passes

typedef unsigned long long u64;
typedef unsigned int u32;

__device__ inline u64 shfl64(u64 v, int src) {
  int lo = __shfl((int)(u32)v, src, 64);
  int hi = __shfl((int)(v >> 32), src, 64);
  return ((u64)(u32)hi << 32) | (u32)lo;
}

// Exact replication of RN(inter/denom) > 0.5 without fdiv:
// RN(a/b) > 0.5  <=>  a/b > 0.5 + 2^-25 (tie rounds-to-even to 0.5)
//               <=>  a * 2^25 > b * (2^24 + 1), both products exact in f64.
__device__ __forceinline__ bool iou_gt_half(float4 bi, float ai,
                                            float4 bj, float aj) {
  #pragma clang fp contract(off)
  float iw = fmaxf(fminf(bi.z, bj.z) - fmaxf(bi.x, bj.x), 0.0f);
  float ih = fmaxf(fminf(bi.w, bj.w) - fmaxf(bi.y, bj.y), 0.0f);
  float inter = iw * ih;
  float denom = ai + aj - inter + 1e-9f;
  return (double)inter * 33554432.0 > (double)denom * 16777217.0;
}

// ---------------------------------------------------------------------------
// Workspace layout (small part total 1,624,320 B - NO overlaps):
//   T16 @0 (320) | prefA @320 | tgtA @640 | cnt @960
//   top_s @1280 (320000) | top_idx @321280 (320000) | cls_out @641280 (40960)
//   ghistA @682240 (40960) | ghistB @723200 (81920) | cand @805120 (819200)
//   maskG @1624320 (10,240,000)   [only if ws_size >= 11,864,320]
// ---------------------------------------------------------------------------
#define OFF_T16    0
#define OFF_PREFA  320
#define OFF_TGTA   640
#define OFF_CNT    960
#define OFF_TOPS   1280
#define OFF_TOPI   321280
#define OFF_CLSOUT 641280
#define OFF_GHA    682240
#define OFF_GHB    723200
#define OFF_CAND   805120
#define OFF_MASK   1624320
#define MASK_BYTES (80ull * TOPK * 16 * 8)

// ---------------------------------------------------------------------------
// Pass A: level-0 histogram, bins = float-bits >> 23 (clamped to 127).
// ---------------------------------------------------------------------------
__global__ __launch_bounds__(256) void k_histA(
    const float* __restrict__ S, u32* __restrict__ gh) {
  __shared__ u32 h[N_CLS * 129];
  for (int i = threadIdx.x; i < N_CLS * 129; i += 256) h[i] = 0;
  __syncthreads();
  const int per = NELEM / 4 / NBLK;
  const float4* S4 = (const float4*)S;
  const int v0 = blockIdx.x * per;
  for (int v = v0 + threadIdx.x; v < v0 + per; v += 256) {
    float4 f = S4[v];
    int c0 = (v * 4) % N_CLS;
    u32 b0 = __float_as_uint(f.x) >> 23; if (b0 > 127u) b0 = 127u;
    u32 b1 = __float_as_uint(f.y) >> 23; if (b1 > 127u) b1 = 127u;
    u32 b2 = __float_as_uint(f.z) >> 23; if (b2 > 127u) b2 = 127u;
    u32 b3 = __float_as_uint(f.w) >> 23; if (b3 > 127u) b3 = 127u;
    atomicAdd(&h[(c0 + 0) * 129 + b0], 1u);
    atomicAdd(&h[(c0 + 1) * 129 + b1], 1u);
    atomicAdd(&h[(c0 + 2) * 129 + b2], 1u);
    atomicAdd(&h[(c0 + 3) * 129 + b3], 1u);
  }
  __syncthreads();
  for (int i = threadIdx.x; i < N_CLS * 128; i += 256) {
    u32 v = h[(i >> 7) * 129 + (i & 127)];
    if (v) atomicAdd(&gh[i], v);
  }
}

__global__ __launch_bounds__(256) void k_thrA(
    const u32* __restrict__ gh, u32* __restrict__ prefA, u32* __restrict__ tgtA) {
  __shared__ u32 h[N_CLS * 129];
  for (int i = threadIdx.x; i < N_CLS * 128; i += 256)
    h[(i >> 7) * 129 + (i & 127)] = gh[i];
  __syncthreads();
  const int c = threadIdx.x;
  if (c >= N_CLS) return;
  u32 acc = 0;
  for (int b = 127; b >= 0; --b) {
    u32 hv = h[c * 129 + b];
    acc += hv;
    if (acc >= TOPK) { prefA[c] = (u32)b; tgtA[c] = TOPK - (acc - hv); return; }
  }
  prefA[c] = 0; tgtA[c] = TOPK;
}

// ---------------------------------------------------------------------------
// Pass B: level-1 histogram over bits [22:15] for elements in the level-0 bin.
// ---------------------------------------------------------------------------
__global__ __launch_bounds__(256) void k_histB(
    const float* __restrict__ S, const u32* __restrict__ prefA,
    u32* __restrict__ gh) {
  __shared__ u32 h[N_CLS * 257];
  __shared__ u32 pA[N_CLS];
  for (int i = threadIdx.x; i < N_CLS * 257; i += 256) h[i] = 0;
  for (int i = threadIdx.x; i < N_CLS; i += 256) pA[i] = prefA[i];
  __syncthreads();
  const int per = NELEM / 4 / NBLK;
  const float4* S4 = (const float4*)S;
  const int v0 = blockIdx.x * per;
  for (int v = v0 + threadIdx.x; v < v0 + per; v += 256) {
    float4 f = S4[v];
    int c0 = (v * 4) % N_CLS;
    u32 bb[4] = {__float_as_uint(f.x), __float_as_uint(f.y),
                 __float_as_uint(f.z), __float_as_uint(f.w)};
    #pragma unroll
    for (int k = 0; k < 4; ++k) {
      u32 e = bb[k] >> 23; if (e > 127u) e = 127u;
      if (e == pA[c0 + k])
        atomicAdd(&h[(c0 + k) * 257 + ((bb[k] >> 15) & 0xFF)], 1u);
    }
  }
  __syncthreads();
  for (int i = threadIdx.x; i < N_CLS * 256; i += 256) {
    u32 v = h[(i >> 8) * 257 + (i & 255)];
    if (v) atomicAdd(&gh[i], v);
  }
}

__global__ __launch_bounds__(256) void k_thrB(
    const u32* __restrict__ gh, const u32* __restrict__ prefA,
    const u32* __restrict__ tgtA, u32* __restrict__ T16) {
  __shared__ u32 h[N_CLS * 257];
  for (int i = threadIdx.x; i < N_CLS * 256; i += 256)
    h[(i >> 8) * 257 + (i & 255)] = gh[i];
  __syncthreads();
  const int c = threadIdx.x;
  if (c >= N_CLS) return;
  const u32 tgt = tgtA[c];
  u32 acc = 0, B1 = 0;
  for (int b = 255; b >= 0; --b) {
    acc += h[c * 257 + b];
    if (acc >= tgt) { B1 = (u32)b; break; }
  }
  T16[c] = (prefA[c] << 23) | (B1 << 15);
}

// ---------------------------------------------------------------------------
// Scatter, two-phase: LDS per-class count -> ONE global atomicAdd per
// (block,class) -> re-read + place at reserved offsets.
// ---------------------------------------------------------------------------
__global__ __launch_bounds__(256) void k_scatter(
    const float* __restrict__ S, const u32* __restrict__ T16,
    u32* __restrict__ cnt, u64* __restrict__ cand) {
  __shared__ u32 tl[N_CLS];
  __shared__ u32 lcnt[N_CLS];
  __shared__ u32 gbase[N_CLS];
  for (int i = threadIdx.x; i < N_CLS; i += 256) { tl[i] = T16[i]; lcnt[i] = 0; }
  __syncthreads();
  const int per = NELEM / 4 / NBLK;
  const float4* S4 = (const float4*)S;
  const int v0 = blockIdx.x * per;
  for (int v = v0 + threadIdx.x; v < v0 + per; v += 256) {
    float4 f = S4[v];
    const int c0 = (v * 4) % N_CLS;
    u32 bb[4] = {__float_as_uint(f.x), __float_as_uint(f.y),
                 __float_as_uint(f.z), __float_as_uint(f.w)};
    #pragma unroll
    for (int k = 0; k < 4; ++k)
      if (bb[k] >= tl[c0 + k]) atomicAdd(&lcnt[c0 + k], 1u);
  }
  __syncthreads();
  for (int i = threadIdx.x; i < N_CLS; i += 256) {
    u32 n = lcnt[i];
    gbase[i] = n ? atomicAdd(&cnt[i], n) : 0u;
    lcnt[i] = 0;
  }
  __syncthreads();
  for (int v = v0 + threadIdx.x; v < v0 + per; v += 256) {
    float4 f = S4[v];
    const int base = v * 4;
    const int c0 = base % N_CLS;
    const u32 row = (u32)(base / N_CLS);
    u32 bb[4] = {__float_as_uint(f.x), __float_as_uint(f.y),
                 __float_as_uint(f.z), __float_as_uint(f.w)};
    #pragma unroll
    for (int k = 0; k < 4; ++k) {
      if (bb[k] >= tl[c0 + k]) {
        u32 p = gbase[c0 + k] + atomicAdd(&lcnt[c0 + k], 1u);
        if (p < CANDS)
          cand[(size_t)(c0 + k) * CANDS + p] = ((u64)bb[k] << 32) | (u32)(~row);
      }
    }
  }
}

// ---------------------------------------------------------------------------
// Per-class bitonic sort -> top-1000 scores + box indices. 512 threads.
// ---------------------------------------------------------------------------
__global__ __launch_bounds__(512) void k_sort(
    const u64* __restrict__ cand, const u32* __restrict__ cnt,
    float* __restrict__ top_s, u32* __restrict__ top_idx) {
  const int c = blockIdx.x, t = threadIdx.x;
  __shared__ u64 keys[SORTN];
  u32 n = cnt[c]; if (n > CANDS) n = CANDS;
  for (int i = t; i < SORTN; i += 512)
    keys[i] = (i < (int)n) ? cand[(size_t)c * CANDS + i] : 0ull;
  __syncthreads();
  for (int k = 2; k <= SORTN; k <<= 1)
    for (int j = k >> 1; j > 0; j >>= 1) {
      for (int p = t; p < SORTN / 2; p += 512) {
        int i  = ((p & ~(j - 1)) << 1) | (p & (j - 1));
        int ix = i | j;
        bool up = (i & k) == 0;
        u64 a = keys[i], b = keys[ix];
        if (up ? (a < b) : (a > b)) { keys[i] = b; keys[ix] = a; }
      }
      __syncthreads();
    }
  for (int i = t; i < TOPK; i += 512) {
    u64 kk = keys[i];
    u32 idx = ~(u32)kk;
    if (kk == 0ull || idx >= N_DET) idx = 0;
    top_s[c * TOPK + i] = __uint_as_float((u32)(kk >> 32));
    top_idx[c * TOPK + i] = idx;
  }
}

// ---------------------------------------------------------------------------
// PATH P (big ws): mask kernel over the whole machine.
// Grid (80 classes, 25 row-blocks of 40 rows), 256 thr.
// ---------------------------------------------------------------------------
__global__ __launch_bounds__(256) void k_mask(
    const u32* __restrict__ top_idx, const float* __restrict__ boxes,
    u64* __restrict__ maskG) {
  const int c = blockIdx.x;
  const int tid = threadIdx.x, wave = tid >> 6, lane = tid & 63;
  __shared__ float4 sbox[TOPK];
  __shared__ float sarea[TOPK];
  for (int i = tid; i < TOPK; i += 256) {
    u32 idx = top_idx[c * TOPK + i];
    if (idx >= N_DET) idx = 0;
    float4 b = ((const float4*)boxes)[idx];
    sbox[i] = b;
    sarea[i] = (b.z - b.x) * (b.w - b.y);
  }
  __syncthreads();
  float4 cb[16]; float ca[16];
  #pragma unroll
  for (int s = 0; s < 16; ++s) {
    int j = s * 64 + lane;
    cb[s] = (j < TOPK) ? sbox[j] : make_float4(0.f, 0.f, 0.f, 0.f);
    ca[s] = (j < TOPK) ? sarea[j] : 0.f;
  }
  for (int rr = 0; rr < 10; ++rr) {
    const int i = blockIdx.y * 40 + wave * 10 + rr;
    float4 bi = sbox[i];
    float ai = sarea[i];
    const int s0 = i >> 6;
    u64 w = 0;
    #pragma unroll
    for (int s = 0; s < 16; ++s) {
      if (s >= s0) {
        int j = s * 64 + lane;
        bool sup = iou_gt_half(bi, ai, cb[s], ca[s]);
        if (s == s0) sup &= (j > i);
        u64 bal = __ballot(sup);
        if (lane == s) w = bal;
      }
    }
    if (lane < 16) maskG[((size_t)c * TOPK + i) * 16 + lane] = w;
  }
}

// ---------------------------------------------------------------------------
// PATH P: serial greedy sweep, one wave per class, 16-deep prefetch.
// ---------------------------------------------------------------------------
__global__ __launch_bounds__(64) void k_sweep(
    const float* __restrict__ top_s, const u64* __restrict__ maskG,
    float* __restrict__ cls_out) {
  const int c = blockIdx.x;
  const int lane = threadIdx.x;
  const u32* M32 = (const u32*)(maskG + (size_t)c * TOPK * 16);
  u64 kw = 0;
  for (int s = 0; s < 16; ++s) {
    int j = s * 64 + lane;
    bool valid = (j < TOPK) && (top_s[c * TOPK + j] > CONF);
    u64 bal = __ballot(valid);
    if (lane == s) kw = bal;
  }
  u32 keep32 = (u32)(shfl64(kw, lane >> 1) >> ((lane & 1) * 32));
  const bool ld = lane < 32;
  u32 rbuf[16];
  #pragma unroll
  for (int d = 0; d < 16; ++d)
    rbuf[d] = ld ? M32[d * 32 + lane] : 0u;
  for (int ib = 0; ib + 16 <= TOPK; ib += 16) {
    #pragma unroll
    for (int d = 0; d < 16; ++d) {
      const int i = ib + d;
      u32 wv = __builtin_amdgcn_readlane(keep32, i >> 5);
      if ((wv >> (i & 31)) & 1u) keep32 &= ~rbuf[d];
      int nx = ib + 16 + d;
      rbuf[d] = (ld && nx < TOPK) ? M32[nx * 32 + lane] : 0u;
    }
  }
  #pragma unroll
  for (int d = 0; d < 8; ++d) {  // tail rows 992..999
    const int i = 992 + d;
    u32 wv = __builtin_amdgcn_readlane(keep32, i >> 5);
    if ((wv >> (i & 31)) & 1u) keep32 &= ~rbuf[d];
  }
  int base = 0;
  #pragma unroll
  for (int s = 0; s < 16; ++s) {
    u32 lo = __builtin_amdgcn_readlane(keep32, 2 * s);
    u32 hi = __builtin_amdgcn_readlane(keep32, 2 * s + 1);
    u64 w = ((u64)hi << 32) | lo;
    int pos = base + __popcll(w & ((1ull << lane) - 1ull));
    if (((w >> lane) & 1ull) && pos < 100)
      cls_out[c * 128 + pos] = top_s[c * TOPK + s * 64 + lane];
    base += __popcll(w);
  }
}

// ---------------------------------------------------------------------------
// PATH Q (small ws): fused mask(LDS)+sweep, 16 waves, 1 block/CU.
// ---------------------------------------------------------------------------
__global__ __launch_bounds__(1024) void k_nms(
    const float* __restrict__ top_s, const u32* __restrict__ top_idx,
    const float* __restrict__ boxes, float* __restrict__ cls_out) {
  const int c = blockIdx.x;
  const int tid = threadIdx.x, wave = tid >> 6, lane = tid & 63;
  __shared__ float4 sbox[TOPK];
  __shared__ float sarea[TOPK];
  __shared__ u64 maskL[TOPK * 16];

  for (int i = tid; i < TOPK; i += 1024) {
    u32 idx = top_idx[c * TOPK + i];
    if (idx >= N_DET) idx = 0;
    float4 b = ((const float4*)boxes)[idx];
    sbox[i] = b;
    sarea[i] = (b.z - b.x) * (b.w - b.y);
  }
  __syncthreads();

  float4 cb[16]; float ca[16];
  #pragma unroll
  for (int s = 0; s < 16; ++s) {
    int j = s * 64 + lane;
    cb[s] = (j < TOPK) ? sbox[j] : make_float4(0.f, 0.f, 0.f, 0.f);
    ca[s] = (j < TOPK) ? sarea[j] : 0.f;
  }

  for (int i = wave; i < TOPK; i += 16) {
    float4 bi = sbox[i];
    float ai = sarea[i];
    const int s0 = i >> 6;
    u64 w = 0;
    #pragma unroll
    for (int s = 0; s < 16; ++s) {
      if (s >= s0) {
        int j = s * 64 + lane;
        bool sup = iou_gt_half(bi, ai, cb[s], ca[s]);
        if (s == s0) sup &= (j > i);
        u64 bal = __ballot(sup);
        if (lane == s) w = bal;
      }
    }
    if (lane < 16) maskL[i * 16 + lane] = w;
  }
  __syncthreads();

  if (wave == 0) {
    u64 kw = 0;
    for (int s = 0; s < 16; ++s) {
      int j = s * 64 + lane;
      bool valid = (j < TOPK) && (top_s[c * TOPK + j] > CONF);
      u64 bal = __ballot(valid);
      if (lane == s) kw = bal;
    }
    u32 keep32 = (u32)(shfl64(kw, lane >> 1) >> ((lane & 1) * 32));
    const u32* M32 = (const u32*)maskL;
    const bool ld = lane < 32;
    u32 rbuf[8];
    #pragma unroll
    for (int d = 0; d < 8; ++d)
      rbuf[d] = ld ? M32[d * 32 + lane] : 0u;
    for (int ib = 0; ib < TOPK; ib += 8) {
      #pragma unroll
      for (int d = 0; d < 8; ++d) {
        const int i = ib + d;
        u32 wv = __builtin_amdgcn_readlane(keep32, i >> 5);
        if ((wv >> (i & 31)) & 1u) keep32 &= ~rbuf[d];
        int nx = ib + 8 + d;
        rbuf[d] = (ld && nx < TOPK) ? M32[nx * 32 + lane] : 0u;
      }
    }
    int base = 0;
    #pragma unroll
    for (int s = 0; s < 16; ++s) {
      u32 lo = __builtin_amdgcn_readlane(keep32, 2 * s);
      u32 hi = __builtin_amdgcn_readlane(keep32, 2 * s + 1);
      u64 w = ((u64)hi << 32) | lo;
      int pos = base + __popcll(w & ((1ull << lane) - 1ull));
      if (((w >> lane) & 1ull) && pos < 100)
        cls_out[c * 128 + pos] = top_s[c * TOPK + s * 64 + lane];
      base += __popcll(w);
    }
  }
}

// ---------------------------------------------------------------------------
// Global top-100, SINGLE-WAVE (64 thr), zero multi-wave barriers.
// R9 found a fixed ~1.2 us per __syncthreads round in single-block
// multi-wave kernels; a wave64 runs lockstep and its LDS ops complete in
// program order, so histogram-select + 256-bitonic can run barrier-free.
// Fallbacks (nc>256 -> 1024-sort; nc>1024 -> full 8192-sort) keep it exact.
// ---------------------------------------------------------------------------
__global__ __launch_bounds__(64) void k_final(
    const float* __restrict__ cls_out, float* __restrict__ out) {
  __shared__ u32 hist[16384];   // 64 KB
  __shared__ u32 vals[8192];    // 32 KB
  __shared__ u32 cands[1024];   //  4 KB
  __shared__ u32 ls[64];
  __shared__ u32 sThr;
  const int lane = threadIdx.x;

  uint4 z4 = make_uint4(0u, 0u, 0u, 0u);
  for (int i = lane; i < 4096; i += 64) ((uint4*)hist)[i] = z4;
  for (int i = lane; i < 2048; i += 64) ((uint4*)vals)[i] = z4;
  for (int i = lane; i < 256; i += 64) ((uint4*)cands)[i] = z4;
  __syncthreads();  // single wave: cheap

  // load + histogram (zeros land in bin 0)
  for (int i = lane; i < 8000; i += 64) {
    u32 b = __float_as_uint(cls_out[(i / 100) * 128 + (i % 100)]);
    vals[i] = b;
    u32 bin = b >> 17; if (bin > 16383u) bin = 16383u;
    atomicAdd(&hist[bin], 1u);
  }
  __syncthreads();

  // lane l owns bins [l*256, l*256+256): local sum
  u32 lsum = 0;
  for (int k = 0; k < 256; ++k) lsum += hist[lane * 256 + k];
  ls[lane] = lsum;
  __syncthreads();
  // strictly-above-chunk suffix (broadcast reads from tiny LDS table)
  u32 above = 0;
  for (int l2 = lane + 1; l2 < 64; ++l2) above += ls[l2];
  // unique crossing lane walks its chunk downward to find threshold bin
  if (above < 100u && above + lsum >= 100u) {
    u32 acc = above;
    int b = lane * 256 + 255;
    for (; b > lane * 256; --b) {
      acc += hist[b];
      if (acc >= 100u) break;
    }
    if (acc < 100u) b = lane * 256;  // crossing must be in this chunk
    sThr = (u32)b << 17;
  }
  __syncthreads();
  const u32 thr = sThr;

  // ballot-prefix compaction of candidates >= thr
  u32 base = 0;
  for (int i = lane; i < 8000; i += 64) {
    u32 v = vals[i];
    bool take = (v >= thr);
    u64 m = __ballot(take);
    if (take) {
      u32 pos = base + (u32)__popcll(m & ((1ull << lane) - 1ull));
      if (pos < 1024u) cands[pos] = v;
    }
    base += (u32)__popcll(m);
  }
  __syncthreads();
  const u32 nc = base;

  if (nc <= 1024u) {
    const int n = (nc <= 256u) ? 256 : 1024;
    if (n == 1024) {  // pad 256..1023 if the small pre-zero didn't cover
      for (int i = lane + 256; i < 1024; i += 64)
        if (i >= (int)nc) cands[i] = 0u;
      __builtin_amdgcn_wave_barrier();
    }
    for (int k = 2; k <= n; k <<= 1)
      for (int j = k >> 1; j > 0; j >>= 1) {
        for (int p = lane; p < n / 2; p += 64) {
          int i  = ((p & ~(j - 1)) << 1) | (p & (j - 1));
          int ix = i | j;
          bool up = (i & k) == 0;
          u32 a = cands[i], b = cands[ix];
          if (up ? (a < b) : (a > b)) { cands[i] = b; cands[ix] = a; }
        }
        __builtin_amdgcn_wave_barrier();
      }
    if (lane < 64) out[lane] = __uint_as_float(cands[lane]);
    if (lane < 36) out[lane + 64] = __uint_as_float(cands[lane + 64]);
  } else {
    // adversarial tie-flood: exact full sort of all 8192 (slow, correct)
    for (int k = 2; k <= 8192; k <<= 1)
      for (int j = k >> 1; j > 0; j >>= 1) {
        for (int p = lane; p < 4096; p += 64) {
          int i  = ((p & ~(j - 1)) << 1) | (p & (j - 1));
          int ix = i | j;
          bool up = (i & k) == 0;
          u32 a = vals[i], b = vals[ix];
          if (up ? (a < b) : (a > b)) { vals[i] = b; vals[ix] = a; }
        }
        __builtin_amdgcn_wave_barrier();
      }
    if (lane < 64) out[lane] = __uint_as_float(vals[lane]);
    if (lane < 36) out[lane + 64] = __uint_as_float(vals[lane + 64]);
  }
}

extern "C" void kernel_launch(void* const* d_in, const int* in_sizes, int n_in,
                              void* d_out, int out_size, void* d_ws, size_t ws_size,
                              hipStream_t stream) {
  const float* scores = (const float*)d_in[0];
  const float* boxes  = (const float*)d_in[1];
  float* out = (float*)d_out;
  char* ws = (char*)d_ws;

  u32* T16     = (u32*)(ws + OFF_T16);
  u32* prefA   = (u32*)(ws + OFF_PREFA);
  u32* tgtA    = (u32*)(ws + OFF_TGTA);
  u32* cnt     = (u32*)(ws + OFF_CNT);
  float* top_s = (float*)(ws + OFF_TOPS);
  u32* top_idx = (u32*)(ws + OFF_TOPI);
  float* cls_out = (float*)(ws + OFF_CLSOUT);
  u32* ghistA  = (u32*)(ws + OFF_GHA);
  u32* ghistB  = (u32*)(ws + OFF_GHB);
  u64* cand    = (u64*)(ws + OFF_CAND);
  u64* maskG   = (u64*)(ws + OFF_MASK);

  const bool bigws = (ws_size >= (size_t)OFF_MASK + MASK_BYTES);

  hipMemsetAsync(ws, 0, 1280, stream);
  hipMemsetAsync(ws + OFF_GHA, 0, 40960 + 81920, stream);
  hipMemsetAsync(cls_out, 0, N_CLS * 128 * sizeof(float), stream);

  k_histA<<<NBLK, 256, 0, stream>>>(scores, ghistA);
  k_thrA<<<1, 256, 0, stream>>>(ghistA, prefA, tgtA);
  k_histB<<<NBLK, 256, 0, stream>>>(scores, prefA, ghistB);
  k_thrB<<<1, 256, 0, stream>>>(ghistB, prefA, tgtA, T16);
  k_scatter<<<NBLK, 256, 0, stream>>>(scores, T16, cnt, cand);
  k_sort<<<N_CLS, 512, 0, stream>>>(cand, cnt, top_s, top_idx);
  if (bigws) {
    k_mask<<<dim3(N_CLS, 25), 256, 0, stream>>>(top_idx, boxes, maskG);
    k_sweep<<<N_CLS, 64, 0, stream>>>(top_s, maskG, cls_out);
  } else {
    k_nms<<<N_CLS, 1024, 0, stream>>>(top_s, top_idx, boxes, cls_out);
  }
  k_final<<<1, 64, 0, stream>>>(cls_out, out);
}

// Round 11
// 263.712 us; speedup vs baseline: 3.5606x; 3.5606x over previous
//
#include <hip/hip_runtime.h>
#include <stdint.h>

#define N_DET 20000
#define N_CLS 80
#define NELEM (N_DET * N_CLS)
#define TOPK  1000
#define CONF  0.05f
#define CANDS 1280
#define SORTN 2048
#define NBLK  40   // blocks for hist/scatter passes

typedef unsigned long long u64;
typedef unsigned int u32;

__device__ inline u64 shfl64(u64 v, int src) {
  int lo = __shfl((int)(u32)v, src, 64);
  int hi = __shfl((int)(v >> 32), src, 64);
  return ((u64)(u32)hi << 32) | (u32)lo;
}

// Exact replication of RN(inter/denom) > 0.5 without fdiv:
// RN(a/b) > 0.5  <=>  a/b > 0.5 + 2^-25 (tie rounds-to-even to 0.5)
//               <=>  a * 2^25 > b * (2^24 + 1), both products exact in f64.
__device__ __forceinline__ bool iou_gt_half(float4 bi, float ai,
                                            float4 bj, float aj) {
  #pragma clang fp contract(off)
  float iw = fmaxf(fminf(bi.z, bj.z) - fmaxf(bi.x, bj.x), 0.0f);
  float ih = fmaxf(fminf(bi.w, bj.w) - fmaxf(bi.y, bj.y), 0.0f);
  float inter = iw * ih;
  float denom = ai + aj - inter + 1e-9f;
  return (double)inter * 33554432.0 > (double)denom * 16777217.0;
}

// ---------------------------------------------------------------------------
// Workspace layout (small part total 1,624,320 B - NO overlaps):
//   T16 @0 (320) | prefA @320 | tgtA @640 | cnt @960
//   top_s @1280 (320000) | top_idx @321280 (320000) | cls_out @641280 (40960)
//   ghistA @682240 (40960) | ghistB @723200 (81920) | cand @805120 (819200)
//   maskG @1624320 (10,240,000)   [only if ws_size >= 11,864,320]
// ---------------------------------------------------------------------------
#define OFF_T16    0
#define OFF_PREFA  320
#define OFF_TGTA   640
#define OFF_CNT    960
#define OFF_TOPS   1280
#define OFF_TOPI   321280
#define OFF_CLSOUT 641280
#define OFF_GHA    682240
#define OFF_GHB    723200
#define OFF_CAND   805120
#define OFF_MASK   1624320
#define MASK_BYTES (80ull * TOPK * 16 * 8)

// ---------------------------------------------------------------------------
// Pass A: level-0 histogram, bins = float-bits >> 23 (clamped to 127).
// ---------------------------------------------------------------------------
__global__ __launch_bounds__(256) void k_histA(
    const float* __restrict__ S, u32* __restrict__ gh) {
  __shared__ u32 h[N_CLS * 129];
  for (int i = threadIdx.x; i < N_CLS * 129; i += 256) h[i] = 0;
  __syncthreads();
  const int per = NELEM / 4 / NBLK;
  const float4* S4 = (const float4*)S;
  const int v0 = blockIdx.x * per;
  for (int v = v0 + threadIdx.x; v < v0 + per; v += 256) {
    float4 f = S4[v];
    int c0 = (v * 4) % N_CLS;
    u32 b0 = __float_as_uint(f.x) >> 23; if (b0 > 127u) b0 = 127u;
    u32 b1 = __float_as_uint(f.y) >> 23; if (b1 > 127u) b1 = 127u;
    u32 b2 = __float_as_uint(f.z) >> 23; if (b2 > 127u) b2 = 127u;
    u32 b3 = __float_as_uint(f.w) >> 23; if (b3 > 127u) b3 = 127u;
    atomicAdd(&h[(c0 + 0) * 129 + b0], 1u);
    atomicAdd(&h[(c0 + 1) * 129 + b1], 1u);
    atomicAdd(&h[(c0 + 2) * 129 + b2], 1u);
    atomicAdd(&h[(c0 + 3) * 129 + b3], 1u);
  }
  __syncthreads();
  for (int i = threadIdx.x; i < N_CLS * 128; i += 256) {
    u32 v = h[(i >> 7) * 129 + (i & 127)];
    if (v) atomicAdd(&gh[i], v);
  }
}

__global__ __launch_bounds__(256) void k_thrA(
    const u32* __restrict__ gh, u32* __restrict__ prefA, u32* __restrict__ tgtA) {
  __shared__ u32 h[N_CLS * 129];
  for (int i = threadIdx.x; i < N_CLS * 128; i += 256)
    h[(i >> 7) * 129 + (i & 127)] = gh[i];
  __syncthreads();
  const int c = threadIdx.x;
  if (c >= N_CLS) return;
  u32 acc = 0;
  for (int b = 127; b >= 0; --b) {
    u32 hv = h[c * 129 + b];
    acc += hv;
    if (acc >= TOPK) { prefA[c] = (u32)b; tgtA[c] = TOPK - (acc - hv); return; }
  }
  prefA[c] = 0; tgtA[c] = TOPK;
}

// ---------------------------------------------------------------------------
// Pass B: level-1 histogram over bits [22:15] for elements in the level-0 bin.
// ---------------------------------------------------------------------------
__global__ __launch_bounds__(256) void k_histB(
    const float* __restrict__ S, const u32* __restrict__ prefA,
    u32* __restrict__ gh) {
  __shared__ u32 h[N_CLS * 257];
  __shared__ u32 pA[N_CLS];
  for (int i = threadIdx.x; i < N_CLS * 257; i += 256) h[i] = 0;
  for (int i = threadIdx.x; i < N_CLS; i += 256) pA[i] = prefA[i];
  __syncthreads();
  const int per = NELEM / 4 / NBLK;
  const float4* S4 = (const float4*)S;
  const int v0 = blockIdx.x * per;
  for (int v = v0 + threadIdx.x; v < v0 + per; v += 256) {
    float4 f = S4[v];
    int c0 = (v * 4) % N_CLS;
    u32 bb[4] = {__float_as_uint(f.x), __float_as_uint(f.y),
                 __float_as_uint(f.z), __float_as_uint(f.w)};
    #pragma unroll
    for (int k = 0; k < 4; ++k) {
      u32 e = bb[k] >> 23; if (e > 127u) e = 127u;
      if (e == pA[c0 + k])
        atomicAdd(&h[(c0 + k) * 257 + ((bb[k] >> 15) & 0xFF)], 1u);
    }
  }
  __syncthreads();
  for (int i = threadIdx.x; i < N_CLS * 256; i += 256) {
    u32 v = h[(i >> 8) * 257 + (i & 255)];
    if (v) atomicAdd(&gh[i], v);
  }
}

__global__ __launch_bounds__(256) void k_thrB(
    const u32* __restrict__ gh, const u32* __restrict__ prefA,
    const u32* __restrict__ tgtA, u32* __restrict__ T16) {
  __shared__ u32 h[N_CLS * 257];
  for (int i = threadIdx.x; i < N_CLS * 256; i += 256)
    h[(i >> 8) * 257 + (i & 255)] = gh[i];
  __syncthreads();
  const int c = threadIdx.x;
  if (c >= N_CLS) return;
  const u32 tgt = tgtA[c];
  u32 acc = 0, B1 = 0;
  for (int b = 255; b >= 0; --b) {
    acc += h[c * 257 + b];
    if (acc >= tgt) { B1 = (u32)b; break; }
  }
  T16[c] = (prefA[c] << 23) | (B1 << 15);
}

// ---------------------------------------------------------------------------
// Scatter, two-phase: LDS per-class count -> ONE global atomicAdd per
// (block,class) -> re-read + place at reserved offsets.
// ---------------------------------------------------------------------------
__global__ __launch_bounds__(256) void k_scatter(
    const float* __restrict__ S, const u32* __restrict__ T16,
    u32* __restrict__ cnt, u64* __restrict__ cand) {
  __shared__ u32 tl[N_CLS];
  __shared__ u32 lcnt[N_CLS];
  __shared__ u32 gbase[N_CLS];
  for (int i = threadIdx.x; i < N_CLS; i += 256) { tl[i] = T16[i]; lcnt[i] = 0; }
  __syncthreads();
  const int per = NELEM / 4 / NBLK;
  const float4* S4 = (const float4*)S;
  const int v0 = blockIdx.x * per;
  for (int v = v0 + threadIdx.x; v < v0 + per; v += 256) {
    float4 f = S4[v];
    const int c0 = (v * 4) % N_CLS;
    u32 bb[4] = {__float_as_uint(f.x), __float_as_uint(f.y),
                 __float_as_uint(f.z), __float_as_uint(f.w)};
    #pragma unroll
    for (int k = 0; k < 4; ++k)
      if (bb[k] >= tl[c0 + k]) atomicAdd(&lcnt[c0 + k], 1u);
  }
  __syncthreads();
  for (int i = threadIdx.x; i < N_CLS; i += 256) {
    u32 n = lcnt[i];
    gbase[i] = n ? atomicAdd(&cnt[i], n) : 0u;
    lcnt[i] = 0;
  }
  __syncthreads();
  for (int v = v0 + threadIdx.x; v < v0 + per; v += 256) {
    float4 f = S4[v];
    const int base = v * 4;
    const int c0 = base % N_CLS;
    const u32 row = (u32)(base / N_CLS);
    u32 bb[4] = {__float_as_uint(f.x), __float_as_uint(f.y),
                 __float_as_uint(f.z), __float_as_uint(f.w)};
    #pragma unroll
    for (int k = 0; k < 4; ++k) {
      if (bb[k] >= tl[c0 + k]) {
        u32 p = gbase[c0 + k] + atomicAdd(&lcnt[c0 + k], 1u);
        if (p < CANDS)
          cand[(size_t)(c0 + k) * CANDS + p] = ((u64)bb[k] << 32) | (u32)(~row);
      }
    }
  }
}

// ---------------------------------------------------------------------------
// Per-class bitonic sort -> top-1000 scores + box indices. 512 threads.
// ---------------------------------------------------------------------------
__global__ __launch_bounds__(512) void k_sort(
    const u64* __restrict__ cand, const u32* __restrict__ cnt,
    float* __restrict__ top_s, u32* __restrict__ top_idx) {
  const int c = blockIdx.x, t = threadIdx.x;
  __shared__ u64 keys[SORTN];
  u32 n = cnt[c]; if (n > CANDS) n = CANDS;
  for (int i = t; i < SORTN; i += 512)
    keys[i] = (i < (int)n) ? cand[(size_t)c * CANDS + i] : 0ull;
  __syncthreads();
  for (int k = 2; k <= SORTN; k <<= 1)
    for (int j = k >> 1; j > 0; j >>= 1) {
      for (int p = t; p < SORTN / 2; p += 512) {
        int i  = ((p & ~(j - 1)) << 1) | (p & (j - 1));
        int ix = i | j;
        bool up = (i & k) == 0;
        u64 a = keys[i], b = keys[ix];
        if (up ? (a < b) : (a > b)) { keys[i] = b; keys[ix] = a; }
      }
      __syncthreads();
    }
  for (int i = t; i < TOPK; i += 512) {
    u64 kk = keys[i];
    u32 idx = ~(u32)kk;
    if (kk == 0ull || idx >= N_DET) idx = 0;
    top_s[c * TOPK + i] = __uint_as_float((u32)(kk >> 32));
    top_idx[c * TOPK + i] = idx;
  }
}

// ---------------------------------------------------------------------------
// PATH P (big ws): mask kernel over the whole machine.
// Grid (80 classes, 25 row-blocks of 40 rows), 256 thr.
// ---------------------------------------------------------------------------
__global__ __launch_bounds__(256) void k_mask(
    const u32* __restrict__ top_idx, const float* __restrict__ boxes,
    u64* __restrict__ maskG) {
  const int c = blockIdx.x;
  const int tid = threadIdx.x, wave = tid >> 6, lane = tid & 63;
  __shared__ float4 sbox[TOPK];
  __shared__ float sarea[TOPK];
  for (int i = tid; i < TOPK; i += 256) {
    u32 idx = top_idx[c * TOPK + i];
    if (idx >= N_DET) idx = 0;
    float4 b = ((const float4*)boxes)[idx];
    sbox[i] = b;
    sarea[i] = (b.z - b.x) * (b.w - b.y);
  }
  __syncthreads();
  float4 cb[16]; float ca[16];
  #pragma unroll
  for (int s = 0; s < 16; ++s) {
    int j = s * 64 + lane;
    cb[s] = (j < TOPK) ? sbox[j] : make_float4(0.f, 0.f, 0.f, 0.f);
    ca[s] = (j < TOPK) ? sarea[j] : 0.f;
  }
  for (int rr = 0; rr < 10; ++rr) {
    const int i = blockIdx.y * 40 + wave * 10 + rr;
    float4 bi = sbox[i];
    float ai = sarea[i];
    const int s0 = i >> 6;
    u64 w = 0;
    #pragma unroll
    for (int s = 0; s < 16; ++s) {
      if (s >= s0) {
        int j = s * 64 + lane;
        bool sup = iou_gt_half(bi, ai, cb[s], ca[s]);
        if (s == s0) sup &= (j > i);
        u64 bal = __ballot(sup);
        if (lane == s) w = bal;
      }
    }
    if (lane < 16) maskG[((size_t)c * TOPK + i) * 16 + lane] = w;
  }
}

// ---------------------------------------------------------------------------
// PATH P: serial greedy sweep, one wave per class, 16-deep prefetch.
// ---------------------------------------------------------------------------
__global__ __launch_bounds__(64) void k_sweep(
    const float* __restrict__ top_s, const u64* __restrict__ maskG,
    float* __restrict__ cls_out) {
  const int c = blockIdx.x;
  const int lane = threadIdx.x;
  const u32* M32 = (const u32*)(maskG + (size_t)c * TOPK * 16);
  u64 kw = 0;
  for (int s = 0; s < 16; ++s) {
    int j = s * 64 + lane;
    bool valid = (j < TOPK) && (top_s[c * TOPK + j] > CONF);
    u64 bal = __ballot(valid);
    if (lane == s) kw = bal;
  }
  u32 keep32 = (u32)(shfl64(kw, lane >> 1) >> ((lane & 1) * 32));
  const bool ld = lane < 32;
  u32 rbuf[16];
  #pragma unroll
  for (int d = 0; d < 16; ++d)
    rbuf[d] = ld ? M32[d * 32 + lane] : 0u;
  for (int ib = 0; ib + 16 <= TOPK; ib += 16) {
    #pragma unroll
    for (int d = 0; d < 16; ++d) {
      const int i = ib + d;
      u32 wv = __builtin_amdgcn_readlane(keep32, i >> 5);
      if ((wv >> (i & 31)) & 1u) keep32 &= ~rbuf[d];
      int nx = ib + 16 + d;
      rbuf[d] = (ld && nx < TOPK) ? M32[nx * 32 + lane] : 0u;
    }
  }
  #pragma unroll
  for (int d = 0; d < 8; ++d) {  // tail rows 992..999
    const int i = 992 + d;
    u32 wv = __builtin_amdgcn_readlane(keep32, i >> 5);
    if ((wv >> (i & 31)) & 1u) keep32 &= ~rbuf[d];
  }
  int base = 0;
  #pragma unroll
  for (int s = 0; s < 16; ++s) {
    u32 lo = __builtin_amdgcn_readlane(keep32, 2 * s);
    u32 hi = __builtin_amdgcn_readlane(keep32, 2 * s + 1);
    u64 w = ((u64)hi << 32) | lo;
    int pos = base + __popcll(w & ((1ull << lane) - 1ull));
    if (((w >> lane) & 1ull) && pos < 100)
      cls_out[c * 128 + pos] = top_s[c * TOPK + s * 64 + lane];
    base += __popcll(w);
  }
}

// ---------------------------------------------------------------------------
// PATH Q (small ws): fused mask(LDS)+sweep, 16 waves, 1 block/CU.
// ---------------------------------------------------------------------------
__global__ __launch_bounds__(1024) void k_nms(
    const float* __restrict__ top_s, const u32* __restrict__ top_idx,
    const float* __restrict__ boxes, float* __restrict__ cls_out) {
  const int c = blockIdx.x;
  const int tid = threadIdx.x, wave = tid >> 6, lane = tid & 63;
  __shared__ float4 sbox[TOPK];
  __shared__ float sarea[TOPK];
  __shared__ u64 maskL[TOPK * 16];

  for (int i = tid; i < TOPK; i += 1024) {
    u32 idx = top_idx[c * TOPK + i];
    if (idx >= N_DET) idx = 0;
    float4 b = ((const float4*)boxes)[idx];
    sbox[i] = b;
    sarea[i] = (b.z - b.x) * (b.w - b.y);
  }
  __syncthreads();

  float4 cb[16]; float ca[16];
  #pragma unroll
  for (int s = 0; s < 16; ++s) {
    int j = s * 64 + lane;
    cb[s] = (j < TOPK) ? sbox[j] : make_float4(0.f, 0.f, 0.f, 0.f);
    ca[s] = (j < TOPK) ? sarea[j] : 0.f;
  }

  for (int i = wave; i < TOPK; i += 16) {
    float4 bi = sbox[i];
    float ai = sarea[i];
    const int s0 = i >> 6;
    u64 w = 0;
    #pragma unroll
    for (int s = 0; s < 16; ++s) {
      if (s >= s0) {
        int j = s * 64 + lane;
        bool sup = iou_gt_half(bi, ai, cb[s], ca[s]);
        if (s == s0) sup &= (j > i);
        u64 bal = __ballot(sup);
        if (lane == s) w = bal;
      }
    }
    if (lane < 16) maskL[i * 16 + lane] = w;
  }
  __syncthreads();

  if (wave == 0) {
    u64 kw = 0;
    for (int s = 0; s < 16; ++s) {
      int j = s * 64 + lane;
      bool valid = (j < TOPK) && (top_s[c * TOPK + j] > CONF);
      u64 bal = __ballot(valid);
      if (lane == s) kw = bal;
    }
    u32 keep32 = (u32)(shfl64(kw, lane >> 1) >> ((lane & 1) * 32));
    const u32* M32 = (const u32*)maskL;
    const bool ld = lane < 32;
    u32 rbuf[8];
    #pragma unroll
    for (int d = 0; d < 8; ++d)
      rbuf[d] = ld ? M32[d * 32 + lane] : 0u;
    for (int ib = 0; ib < TOPK; ib += 8) {
      #pragma unroll
      for (int d = 0; d < 8; ++d) {
        const int i = ib + d;
        u32 wv = __builtin_amdgcn_readlane(keep32, i >> 5);
        if ((wv >> (i & 31)) & 1u) keep32 &= ~rbuf[d];
        int nx = ib + 8 + d;
        rbuf[d] = (ld && nx < TOPK) ? M32[nx * 32 + lane] : 0u;
      }
    }
    int base = 0;
    #pragma unroll
    for (int s = 0; s < 16; ++s) {
      u32 lo = __builtin_amdgcn_readlane(keep32, 2 * s);
      u32 hi = __builtin_amdgcn_readlane(keep32, 2 * s + 1);
      u64 w = ((u64)hi << 32) | lo;
      int pos = base + __popcll(w & ((1ull << lane) - 1ull));
      if (((w >> lane) & 1ull) && pos < 100)
        cls_out[c * 128 + pos] = top_s[c * TOPK + s * 64 + lane];
      base += __popcll(w);
    }
  }
}

// ---------------------------------------------------------------------------
// Global top-100 via TWO-LEVEL radix select (256 thr).
// R10 lesson: all kept scores lie in [0.95,1) -> a single bits>>17 histogram
// puts ALL 8000 in one bin and the select degenerates to the full-sort
// fallback every call. Level 1: bits>>17 (8192 bins) -> prefix bin + residual
// target. Level 2: bits[16:3] (16384 bins) within the prefix bin -> threshold
// with 3 unresolved low bits -> ~100-107 candidates -> single-wave lockstep
// bitonic of 512. Fallback (nc>512: adversarial ties) sorts 8192 in h2.
// ---------------------------------------------------------------------------
__global__ __launch_bounds__(256) void k_final(
    const float* __restrict__ cls_out, float* __restrict__ out) {
  __shared__ u32 vals[8000];    // 32000 B
  __shared__ u32 h1[8192];      // 32768 B
  __shared__ u32 h2[16384];     // 65536 B
  __shared__ u32 sfx[256];
  __shared__ u32 cands[512];
  __shared__ u32 sPref, sT2, sThr, scnt;
  const int t = threadIdx.x;

  for (int i = t; i < 8192; i += 256) h1[i] = 0;
  for (int i = t; i < 16384; i += 256) h2[i] = 0;
  for (int i = t; i < 512; i += 256) cands[i] = 0;
  if (t == 0) { sPref = 0; sT2 = 1; sThr = 0; scnt = 0; }
  __syncthreads();

  // load + level-1 histogram (zeros land in bin 0)
  for (int i = t; i < 8000; i += 256) {
    u32 b = __float_as_uint(cls_out[(i / 100) * 128 + (i % 100)]);
    vals[i] = b;
    u32 bin = b >> 17; if (bin > 8191u) bin = 8191u;
    atomicAdd(&h1[bin], 1u);
  }
  __syncthreads();

  // level-1 suffix scan: thread t owns bins [32t, 32t+32)
  {
    const u32 base = t * 32;
    u32 lsum = 0;
    for (int k = 0; k < 32; ++k) lsum += h1[base + k];
    sfx[t] = lsum;
    __syncthreads();
    for (int off = 1; off < 256; off <<= 1) {
      u32 v = (t + off < 256) ? sfx[t + off] : 0u;
      __syncthreads();
      sfx[t] += v;
      __syncthreads();
    }
    u32 above = (t == 255) ? 0u : sfx[t + 1];
    if (above < 100u && above + lsum >= 100u) {
      u32 acc = above;
      int b = (int)base + 31;
      for (; b >= (int)base; --b) {
        acc += h1[b];
        if (acc >= 100u) break;
      }
      sPref = (u32)b;
      sT2 = 100u - (acc - h1[b]);   // in [1,100]
    }
  }
  __syncthreads();
  const u32 pref = sPref, t2 = sT2;

  // level-2 histogram over bits[16:3] for elements in the prefix bin
  for (int i = t; i < 8000; i += 256) {
    u32 b = vals[i];
    u32 bin = b >> 17; if (bin > 8191u) bin = 8191u;
    if (bin == pref) atomicAdd(&h2[(b >> 3) & 0x3FFFu], 1u);
  }
  __syncthreads();

  // level-2 suffix scan: thread t owns bins [64t, 64t+64)
  {
    const u32 base = t * 64;
    u32 lsum = 0;
    for (int k = 0; k < 64; ++k) lsum += h2[base + k];
    sfx[t] = lsum;
    __syncthreads();
    for (int off = 1; off < 256; off <<= 1) {
      u32 v = (t + off < 256) ? sfx[t + off] : 0u;
      __syncthreads();
      sfx[t] += v;
      __syncthreads();
    }
    u32 above = (t == 255) ? 0u : sfx[t + 1];
    if (above < t2 && above + lsum >= t2) {
      u32 acc = above;
      int b = (int)base + 63;
      for (; b >= (int)base; --b) {
        acc += h2[b];
        if (acc >= t2) break;
      }
      sThr = (pref << 17) | ((u32)b << 3);
    }
  }
  __syncthreads();
  const u32 thr = sThr;

  // compact candidates >= thr (expected ~100-107)
  for (int i = t; i < 8000; i += 256) {
    u32 v = vals[i];
    if (v >= thr) {
      u32 p = atomicAdd(&scnt, 1u);
      if (p < 512u) cands[p] = v;
    }
  }
  __syncthreads();
  const u32 nc = scnt;

  if (nc <= 512u) {
    // single-wave lockstep bitonic sort of 512 (desc); no multi-wave barriers
    if (t < 64) {
      for (int k = 2; k <= 512; k <<= 1)
        for (int j = k >> 1; j > 0; j >>= 1) {
          for (int p = t; p < 256; p += 64) {
            int i  = ((p & ~(j - 1)) << 1) | (p & (j - 1));
            int ix = i | j;
            bool up = (i & k) == 0;
            u32 a = cands[i], b = cands[ix];
            if (up ? (a < b) : (a > b)) { cands[i] = b; cands[ix] = a; }
          }
          __builtin_amdgcn_wave_barrier();
        }
      out[t] = __uint_as_float(cands[t]);
      if (t < 36) out[t + 64] = __uint_as_float(cands[t + 64]);
    }
  } else {
    // adversarial tie-flood: exact full sort of 8192 in h2 (reuse as buffer)
    for (int i = t; i < 8192; i += 256) h2[i] = (i < 8000) ? vals[i] : 0u;
    __syncthreads();
    for (int k = 2; k <= 8192; k <<= 1)
      for (int j = k >> 1; j > 0; j >>= 1) {
        for (int p = t; p < 4096; p += 256) {
          int i  = ((p & ~(j - 1)) << 1) | (p & (j - 1));
          int ix = i | j;
          bool up = (i & k) == 0;
          u32 a = h2[i], b = h2[ix];
          if (up ? (a < b) : (a > b)) { h2[i] = b; h2[ix] = a; }
        }
        __syncthreads();
      }
    if (t < 100) out[t] = __uint_as_float(h2[t]);
  }
}

extern "C" void kernel_launch(void* const* d_in, const int* in_sizes, int n_in,
                              void* d_out, int out_size, void* d_ws, size_t ws_size,
                              hipStream_t stream) {
  const float* scores = (const float*)d_in[0];
  const float* boxes  = (const float*)d_in[1];
  float* out = (float*)d_out;
  char* ws = (char*)d_ws;

  u32* T16     = (u32*)(ws + OFF_T16);
  u32* prefA   = (u32*)(ws + OFF_PREFA);
  u32* tgtA    = (u32*)(ws + OFF_TGTA);
  u32* cnt     = (u32*)(ws + OFF_CNT);
  float* top_s = (float*)(ws + OFF_TOPS);
  u32* top_idx = (u32*)(ws + OFF_TOPI);
  float* cls_out = (float*)(ws + OFF_CLSOUT);
  u32* ghistA  = (u32*)(ws + OFF_GHA);
  u32* ghistB  = (u32*)(ws + OFF_GHB);
  u64* cand    = (u64*)(ws + OFF_CAND);
  u64* maskG   = (u64*)(ws + OFF_MASK);

  const bool bigws = (ws_size >= (size_t)OFF_MASK + MASK_BYTES);

  hipMemsetAsync(ws, 0, 1280, stream);
  hipMemsetAsync(ws + OFF_GHA, 0, 40960 + 81920, stream);
  hipMemsetAsync(cls_out, 0, N_CLS * 128 * sizeof(float), stream);

  k_histA<<<NBLK, 256, 0, stream>>>(scores, ghistA);
  k_thrA<<<1, 256, 0, stream>>>(ghistA, prefA, tgtA);
  k_histB<<<NBLK, 256, 0, stream>>>(scores, prefA, ghistB);
  k_thrB<<<1, 256, 0, stream>>>(ghistB, prefA, tgtA, T16);
  k_scatter<<<NBLK, 256, 0, stream>>>(scores, T16, cnt, cand);
  k_sort<<<N_CLS, 512, 0, stream>>>(cand, cnt, top_s, top_idx);
  if (bigws) {
    k_mask<<<dim3(N_CLS, 25), 256, 0, stream>>>(top_idx, boxes, maskG);
    k_sweep<<<N_CLS, 64, 0, stream>>>(top_s, maskG, cls_out);
  } else {
    k_nms<<<N_CLS, 1024, 0, stream>>>(top_s, top_idx, boxes, cls_out);
  }
  k_final<<<1, 256, 0, stream>>>(cls_out, out);
}

// Round 12
// 251.986 us; speedup vs baseline: 3.7263x; 1.0465x over previous
//
#include <hip/hip_runtime.h>
#include <stdint.h>

#define N_DET 20000
#define N_CLS 80
#define NELEM (N_DET * N_CLS)
#define TOPK  1000
#define CONF  0.05f
#define CANDS 1280
#define SORTN 2048
#define NBLK  40   // blocks for hist/scatter passes

typedef unsigned long long u64;
typedef unsigned int u32;

__device__ inline u64 shfl64(u64 v, int src) {
  int lo = __shfl((int)(u32)v, src, 64);
  int hi = __shfl((int)(v >> 32), src, 64);
  return ((u64)(u32)hi << 32) | (u32)lo;
}

// Exact replication of RN(inter/denom) > 0.5 without fdiv:
// RN(a/b) > 0.5  <=>  a/b > 0.5 + 2^-25 (tie rounds-to-even to 0.5)
//               <=>  a * 2^25 > b * (2^24 + 1), both products exact in f64.
__device__ __forceinline__ bool iou_gt_half(float4 bi, float ai,
                                            float4 bj, float aj) {
  #pragma clang fp contract(off)
  float iw = fmaxf(fminf(bi.z, bj.z) - fmaxf(bi.x, bj.x), 0.0f);
  float ih = fmaxf(fminf(bi.w, bj.w) - fmaxf(bi.y, bj.y), 0.0f);
  float inter = iw * ih;
  float denom = ai + aj - inter + 1e-9f;
  return (double)inter * 33554432.0 > (double)denom * 16777217.0;
}

// ---------------------------------------------------------------------------
// Workspace layout (small part total 1,624,320 B - NO overlaps):
//   T16 @0 (320) | prefA @320 | tgtA @640 | cnt @960
//   top_s @1280 (320000) | top_idx @321280 (320000) | cls_out @641280 (40960)
//   ghistA @682240 (40960) | ghistB @723200 (81920) | cand @805120 (819200)
//   maskG @1624320 (10,240,000)   [only if ws_size >= 11,864,320]
// ---------------------------------------------------------------------------
#define OFF_T16    0
#define OFF_PREFA  320
#define OFF_TGTA   640
#define OFF_CNT    960
#define OFF_TOPS   1280
#define OFF_TOPI   321280
#define OFF_CLSOUT 641280
#define OFF_GHA    682240
#define OFF_GHB    723200
#define OFF_CAND   805120
#define OFF_MASK   1624320
#define MASK_BYTES (80ull * TOPK * 16 * 8)

// ---------------------------------------------------------------------------
// Pass A: level-0 histogram, bins = float-bits >> 23 (clamped to 127).
// ---------------------------------------------------------------------------
__global__ __launch_bounds__(256) void k_histA(
    const float* __restrict__ S, u32* __restrict__ gh) {
  __shared__ u32 h[N_CLS * 129];
  for (int i = threadIdx.x; i < N_CLS * 129; i += 256) h[i] = 0;
  __syncthreads();
  const int per = NELEM / 4 / NBLK;
  const float4* S4 = (const float4*)S;
  const int v0 = blockIdx.x * per;
  for (int v = v0 + threadIdx.x; v < v0 + per; v += 256) {
    float4 f = S4[v];
    int c0 = (v * 4) % N_CLS;
    u32 b0 = __float_as_uint(f.x) >> 23; if (b0 > 127u) b0 = 127u;
    u32 b1 = __float_as_uint(f.y) >> 23; if (b1 > 127u) b1 = 127u;
    u32 b2 = __float_as_uint(f.z) >> 23; if (b2 > 127u) b2 = 127u;
    u32 b3 = __float_as_uint(f.w) >> 23; if (b3 > 127u) b3 = 127u;
    atomicAdd(&h[(c0 + 0) * 129 + b0], 1u);
    atomicAdd(&h[(c0 + 1) * 129 + b1], 1u);
    atomicAdd(&h[(c0 + 2) * 129 + b2], 1u);
    atomicAdd(&h[(c0 + 3) * 129 + b3], 1u);
  }
  __syncthreads();
  for (int i = threadIdx.x; i < N_CLS * 128; i += 256) {
    u32 v = h[(i >> 7) * 129 + (i & 127)];
    if (v) atomicAdd(&gh[i], v);
  }
}

__global__ __launch_bounds__(256) void k_thrA(
    const u32* __restrict__ gh, u32* __restrict__ prefA, u32* __restrict__ tgtA) {
  __shared__ u32 h[N_CLS * 129];
  for (int i = threadIdx.x; i < N_CLS * 128; i += 256)
    h[(i >> 7) * 129 + (i & 127)] = gh[i];
  __syncthreads();
  const int c = threadIdx.x;
  if (c >= N_CLS) return;
  u32 acc = 0;
  for (int b = 127; b >= 0; --b) {
    u32 hv = h[c * 129 + b];
    acc += hv;
    if (acc >= TOPK) { prefA[c] = (u32)b; tgtA[c] = TOPK - (acc - hv); return; }
  }
  prefA[c] = 0; tgtA[c] = TOPK;
}

// ---------------------------------------------------------------------------
// Pass B: level-1 histogram over bits [22:15] for elements in the level-0 bin.
// ---------------------------------------------------------------------------
__global__ __launch_bounds__(256) void k_histB(
    const float* __restrict__ S, const u32* __restrict__ prefA,
    u32* __restrict__ gh) {
  __shared__ u32 h[N_CLS * 257];
  __shared__ u32 pA[N_CLS];
  for (int i = threadIdx.x; i < N_CLS * 257; i += 256) h[i] = 0;
  for (int i = threadIdx.x; i < N_CLS; i += 256) pA[i] = prefA[i];
  __syncthreads();
  const int per = NELEM / 4 / NBLK;
  const float4* S4 = (const float4*)S;
  const int v0 = blockIdx.x * per;
  for (int v = v0 + threadIdx.x; v < v0 + per; v += 256) {
    float4 f = S4[v];
    int c0 = (v * 4) % N_CLS;
    u32 bb[4] = {__float_as_uint(f.x), __float_as_uint(f.y),
                 __float_as_uint(f.z), __float_as_uint(f.w)};
    #pragma unroll
    for (int k = 0; k < 4; ++k) {
      u32 e = bb[k] >> 23; if (e > 127u) e = 127u;
      if (e == pA[c0 + k])
        atomicAdd(&h[(c0 + k) * 257 + ((bb[k] >> 15) & 0xFF)], 1u);
    }
  }
  __syncthreads();
  for (int i = threadIdx.x; i < N_CLS * 256; i += 256) {
    u32 v = h[(i >> 8) * 257 + (i & 255)];
    if (v) atomicAdd(&gh[i], v);
  }
}

__global__ __launch_bounds__(256) void k_thrB(
    const u32* __restrict__ gh, const u32* __restrict__ prefA,
    const u32* __restrict__ tgtA, u32* __restrict__ T16) {
  __shared__ u32 h[N_CLS * 257];
  for (int i = threadIdx.x; i < N_CLS * 256; i += 256)
    h[(i >> 8) * 257 + (i & 255)] = gh[i];
  __syncthreads();
  const int c = threadIdx.x;
  if (c >= N_CLS) return;
  const u32 tgt = tgtA[c];
  u32 acc = 0, B1 = 0;
  for (int b = 255; b >= 0; --b) {
    acc += h[c * 257 + b];
    if (acc >= tgt) { B1 = (u32)b; break; }
  }
  T16[c] = (prefA[c] << 23) | (B1 << 15);
}

// ---------------------------------------------------------------------------
// Scatter, two-phase: LDS per-class count -> ONE global atomicAdd per
// (block,class) -> re-read + place at reserved offsets.
// ---------------------------------------------------------------------------
__global__ __launch_bounds__(256) void k_scatter(
    const float* __restrict__ S, const u32* __restrict__ T16,
    u32* __restrict__ cnt, u64* __restrict__ cand) {
  __shared__ u32 tl[N_CLS];
  __shared__ u32 lcnt[N_CLS];
  __shared__ u32 gbase[N_CLS];
  for (int i = threadIdx.x; i < N_CLS; i += 256) { tl[i] = T16[i]; lcnt[i] = 0; }
  __syncthreads();
  const int per = NELEM / 4 / NBLK;
  const float4* S4 = (const float4*)S;
  const int v0 = blockIdx.x * per;
  for (int v = v0 + threadIdx.x; v < v0 + per; v += 256) {
    float4 f = S4[v];
    const int c0 = (v * 4) % N_CLS;
    u32 bb[4] = {__float_as_uint(f.x), __float_as_uint(f.y),
                 __float_as_uint(f.z), __float_as_uint(f.w)};
    #pragma unroll
    for (int k = 0; k < 4; ++k)
      if (bb[k] >= tl[c0 + k]) atomicAdd(&lcnt[c0 + k], 1u);
  }
  __syncthreads();
  for (int i = threadIdx.x; i < N_CLS; i += 256) {
    u32 n = lcnt[i];
    gbase[i] = n ? atomicAdd(&cnt[i], n) : 0u;
    lcnt[i] = 0;
  }
  __syncthreads();
  for (int v = v0 + threadIdx.x; v < v0 + per; v += 256) {
    float4 f = S4[v];
    const int base = v * 4;
    const int c0 = base % N_CLS;
    const u32 row = (u32)(base / N_CLS);
    u32 bb[4] = {__float_as_uint(f.x), __float_as_uint(f.y),
                 __float_as_uint(f.z), __float_as_uint(f.w)};
    #pragma unroll
    for (int k = 0; k < 4; ++k) {
      if (bb[k] >= tl[c0 + k]) {
        u32 p = gbase[c0 + k] + atomicAdd(&lcnt[c0 + k], 1u);
        if (p < CANDS)
          cand[(size_t)(c0 + k) * CANDS + p] = ((u64)bb[k] << 32) | (u32)(~row);
      }
    }
  }
}

// ---------------------------------------------------------------------------
// Per-class bitonic sort -> top-1000 scores + box indices. 512 threads.
// ---------------------------------------------------------------------------
__global__ __launch_bounds__(512) void k_sort(
    const u64* __restrict__ cand, const u32* __restrict__ cnt,
    float* __restrict__ top_s, u32* __restrict__ top_idx) {
  const int c = blockIdx.x, t = threadIdx.x;
  __shared__ u64 keys[SORTN];
  u32 n = cnt[c]; if (n > CANDS) n = CANDS;
  for (int i = t; i < SORTN; i += 512)
    keys[i] = (i < (int)n) ? cand[(size_t)c * CANDS + i] : 0ull;
  __syncthreads();
  for (int k = 2; k <= SORTN; k <<= 1)
    for (int j = k >> 1; j > 0; j >>= 1) {
      for (int p = t; p < SORTN / 2; p += 512) {
        int i  = ((p & ~(j - 1)) << 1) | (p & (j - 1));
        int ix = i | j;
        bool up = (i & k) == 0;
        u64 a = keys[i], b = keys[ix];
        if (up ? (a < b) : (a > b)) { keys[i] = b; keys[ix] = a; }
      }
      __syncthreads();
    }
  for (int i = t; i < TOPK; i += 512) {
    u64 kk = keys[i];
    u32 idx = ~(u32)kk;
    if (kk == 0ull || idx >= N_DET) idx = 0;
    top_s[c * TOPK + i] = __uint_as_float((u32)(kk >> 32));
    top_idx[c * TOPK + i] = idx;
  }
}

// ---------------------------------------------------------------------------
// PATH P (big ws): mask kernel over the whole machine.
// Grid (80 classes, 25 row-blocks of 40 rows), 256 thr.
// ---------------------------------------------------------------------------
__global__ __launch_bounds__(256) void k_mask(
    const u32* __restrict__ top_idx, const float* __restrict__ boxes,
    u64* __restrict__ maskG) {
  const int c = blockIdx.x;
  const int tid = threadIdx.x, wave = tid >> 6, lane = tid & 63;
  __shared__ float4 sbox[TOPK];
  __shared__ float sarea[TOPK];
  for (int i = tid; i < TOPK; i += 256) {
    u32 idx = top_idx[c * TOPK + i];
    if (idx >= N_DET) idx = 0;
    float4 b = ((const float4*)boxes)[idx];
    sbox[i] = b;
    sarea[i] = (b.z - b.x) * (b.w - b.y);
  }
  __syncthreads();
  float4 cb[16]; float ca[16];
  #pragma unroll
  for (int s = 0; s < 16; ++s) {
    int j = s * 64 + lane;
    cb[s] = (j < TOPK) ? sbox[j] : make_float4(0.f, 0.f, 0.f, 0.f);
    ca[s] = (j < TOPK) ? sarea[j] : 0.f;
  }
  for (int rr = 0; rr < 10; ++rr) {
    const int i = blockIdx.y * 40 + wave * 10 + rr;
    float4 bi = sbox[i];
    float ai = sarea[i];
    const int s0 = i >> 6;
    u64 w = 0;
    #pragma unroll
    for (int s = 0; s < 16; ++s) {
      if (s >= s0) {
        int j = s * 64 + lane;
        bool sup = iou_gt_half(bi, ai, cb[s], ca[s]);
        if (s == s0) sup &= (j > i);
        u64 bal = __ballot(sup);
        if (lane == s) w = bal;
      }
    }
    if (lane < 16) maskG[((size_t)c * TOPK + i) * 16 + lane] = w;
  }
}

// ---------------------------------------------------------------------------
// PATH P: sweep v2 (512 thr). R11 found the 1-wave 16-deep global prefetch
// latency-bound at 71 us. Now: 8 waves bulk-stage the class's whole 128 KB
// mask into LDS (coalesced uint4, hundreds of loads in flight), one barrier,
// then wave 0 sweeps from LDS with the 8-deep register prefetch.
// ---------------------------------------------------------------------------
__global__ __launch_bounds__(512) void k_sweep(
    const float* __restrict__ top_s, const u64* __restrict__ maskG,
    float* __restrict__ cls_out) {
  const int c = blockIdx.x;
  const int tid = threadIdx.x, wave = tid >> 6, lane = tid & 63;
  __shared__ u64 maskL[TOPK * 16];  // 128000 B

  // bulk stage: 8000 uint4 = 128 KB, coalesced across 512 threads
  {
    const uint4* src = (const uint4*)(maskG + (size_t)c * TOPK * 16);
    uint4* dst = (uint4*)maskL;
    for (int i = tid; i < TOPK * 16 / 2; i += 512) dst[i] = src[i];
  }
  __syncthreads();

  if (wave == 0) {
    u64 kw = 0;
    for (int s = 0; s < 16; ++s) {
      int j = s * 64 + lane;
      bool valid = (j < TOPK) && (top_s[c * TOPK + j] > CONF);
      u64 bal = __ballot(valid);
      if (lane == s) kw = bal;
    }
    u32 keep32 = (u32)(shfl64(kw, lane >> 1) >> ((lane & 1) * 32));
    const u32* M32 = (const u32*)maskL;
    const bool ld = lane < 32;
    u32 rbuf[8];
    #pragma unroll
    for (int d = 0; d < 8; ++d)
      rbuf[d] = ld ? M32[d * 32 + lane] : 0u;
    for (int ib = 0; ib < TOPK; ib += 8) {
      #pragma unroll
      for (int d = 0; d < 8; ++d) {
        const int i = ib + d;
        u32 wv = __builtin_amdgcn_readlane(keep32, i >> 5);
        if ((wv >> (i & 31)) & 1u) keep32 &= ~rbuf[d];
        int nx = ib + 8 + d;
        rbuf[d] = (ld && nx < TOPK) ? M32[nx * 32 + lane] : 0u;
      }
    }
    int base = 0;
    #pragma unroll
    for (int s = 0; s < 16; ++s) {
      u32 lo = __builtin_amdgcn_readlane(keep32, 2 * s);
      u32 hi = __builtin_amdgcn_readlane(keep32, 2 * s + 1);
      u64 w = ((u64)hi << 32) | lo;
      int pos = base + __popcll(w & ((1ull << lane) - 1ull));
      if (((w >> lane) & 1ull) && pos < 100)
        cls_out[c * 128 + pos] = top_s[c * TOPK + s * 64 + lane];
      base += __popcll(w);
    }
  }
}

// ---------------------------------------------------------------------------
// PATH Q (small ws): fused mask(LDS)+sweep, 16 waves, 1 block/CU.
// ---------------------------------------------------------------------------
__global__ __launch_bounds__(1024) void k_nms(
    const float* __restrict__ top_s, const u32* __restrict__ top_idx,
    const float* __restrict__ boxes, float* __restrict__ cls_out) {
  const int c = blockIdx.x;
  const int tid = threadIdx.x, wave = tid >> 6, lane = tid & 63;
  __shared__ float4 sbox[TOPK];
  __shared__ float sarea[TOPK];
  __shared__ u64 maskL[TOPK * 16];

  for (int i = tid; i < TOPK; i += 1024) {
    u32 idx = top_idx[c * TOPK + i];
    if (idx >= N_DET) idx = 0;
    float4 b = ((const float4*)boxes)[idx];
    sbox[i] = b;
    sarea[i] = (b.z - b.x) * (b.w - b.y);
  }
  __syncthreads();

  float4 cb[16]; float ca[16];
  #pragma unroll
  for (int s = 0; s < 16; ++s) {
    int j = s * 64 + lane;
    cb[s] = (j < TOPK) ? sbox[j] : make_float4(0.f, 0.f, 0.f, 0.f);
    ca[s] = (j < TOPK) ? sarea[j] : 0.f;
  }

  for (int i = wave; i < TOPK; i += 16) {
    float4 bi = sbox[i];
    float ai = sarea[i];
    const int s0 = i >> 6;
    u64 w = 0;
    #pragma unroll
    for (int s = 0; s < 16; ++s) {
      if (s >= s0) {
        int j = s * 64 + lane;
        bool sup = iou_gt_half(bi, ai, cb[s], ca[s]);
        if (s == s0) sup &= (j > i);
        u64 bal = __ballot(sup);
        if (lane == s) w = bal;
      }
    }
    if (lane < 16) maskL[i * 16 + lane] = w;
  }
  __syncthreads();

  if (wave == 0) {
    u64 kw = 0;
    for (int s = 0; s < 16; ++s) {
      int j = s * 64 + lane;
      bool valid = (j < TOPK) && (top_s[c * TOPK + j] > CONF);
      u64 bal = __ballot(valid);
      if (lane == s) kw = bal;
    }
    u32 keep32 = (u32)(shfl64(kw, lane >> 1) >> ((lane & 1) * 32));
    const u32* M32 = (const u32*)maskL;
    const bool ld = lane < 32;
    u32 rbuf[8];
    #pragma unroll
    for (int d = 0; d < 8; ++d)
      rbuf[d] = ld ? M32[d * 32 + lane] : 0u;
    for (int ib = 0; ib < TOPK; ib += 8) {
      #pragma unroll
      for (int d = 0; d < 8; ++d) {
        const int i = ib + d;
        u32 wv = __builtin_amdgcn_readlane(keep32, i >> 5);
        if ((wv >> (i & 31)) & 1u) keep32 &= ~rbuf[d];
        int nx = ib + 8 + d;
        rbuf[d] = (ld && nx < TOPK) ? M32[nx * 32 + lane] : 0u;
      }
    }
    int base = 0;
    #pragma unroll
    for (int s = 0; s < 16; ++s) {
      u32 lo = __builtin_amdgcn_readlane(keep32, 2 * s);
      u32 hi = __builtin_amdgcn_readlane(keep32, 2 * s + 1);
      u64 w = ((u64)hi << 32) | lo;
      int pos = base + __popcll(w & ((1ull << lane) - 1ull));
      if (((w >> lane) & 1ull) && pos < 100)
        cls_out[c * 128 + pos] = top_s[c * TOPK + s * 64 + lane];
      base += __popcll(w);
    }
  }
}

// ---------------------------------------------------------------------------
// Global top-100 via TWO-LEVEL radix select (256 thr).
// Level 1: bits>>17 (8192 bins). Level 2: bits[16:3] within the prefix bin.
// ~100-107 candidates -> single-wave lockstep bitonic of 512.
// Fallback (nc>512: adversarial ties) sorts 8192 in h2.
// ---------------------------------------------------------------------------
__global__ __launch_bounds__(256) void k_final(
    const float* __restrict__ cls_out, float* __restrict__ out) {
  __shared__ u32 vals[8000];    // 32000 B
  __shared__ u32 h1[8192];      // 32768 B
  __shared__ u32 h2[16384];     // 65536 B
  __shared__ u32 sfx[256];
  __shared__ u32 cands[512];
  __shared__ u32 sPref, sT2, sThr, scnt;
  const int t = threadIdx.x;

  for (int i = t; i < 8192; i += 256) h1[i] = 0;
  for (int i = t; i < 16384; i += 256) h2[i] = 0;
  for (int i = t; i < 512; i += 256) cands[i] = 0;
  if (t == 0) { sPref = 0; sT2 = 1; sThr = 0; scnt = 0; }
  __syncthreads();

  for (int i = t; i < 8000; i += 256) {
    u32 b = __float_as_uint(cls_out[(i / 100) * 128 + (i % 100)]);
    vals[i] = b;
    u32 bin = b >> 17; if (bin > 8191u) bin = 8191u;
    atomicAdd(&h1[bin], 1u);
  }
  __syncthreads();

  {
    const u32 base = t * 32;
    u32 lsum = 0;
    for (int k = 0; k < 32; ++k) lsum += h1[base + k];
    sfx[t] = lsum;
    __syncthreads();
    for (int off = 1; off < 256; off <<= 1) {
      u32 v = (t + off < 256) ? sfx[t + off] : 0u;
      __syncthreads();
      sfx[t] += v;
      __syncthreads();
    }
    u32 above = (t == 255) ? 0u : sfx[t + 1];
    if (above < 100u && above + lsum >= 100u) {
      u32 acc = above;
      int b = (int)base + 31;
      for (; b >= (int)base; --b) {
        acc += h1[b];
        if (acc >= 100u) break;
      }
      sPref = (u32)b;
      sT2 = 100u - (acc - h1[b]);   // in [1,100]
    }
  }
  __syncthreads();
  const u32 pref = sPref, t2 = sT2;

  for (int i = t; i < 8000; i += 256) {
    u32 b = vals[i];
    u32 bin = b >> 17; if (bin > 8191u) bin = 8191u;
    if (bin == pref) atomicAdd(&h2[(b >> 3) & 0x3FFFu], 1u);
  }
  __syncthreads();

  {
    const u32 base = t * 64;
    u32 lsum = 0;
    for (int k = 0; k < 64; ++k) lsum += h2[base + k];
    sfx[t] = lsum;
    __syncthreads();
    for (int off = 1; off < 256; off <<= 1) {
      u32 v = (t + off < 256) ? sfx[t + off] : 0u;
      __syncthreads();
      sfx[t] += v;
      __syncthreads();
    }
    u32 above = (t == 255) ? 0u : sfx[t + 1];
    if (above < t2 && above + lsum >= t2) {
      u32 acc = above;
      int b = (int)base + 63;
      for (; b >= (int)base; --b) {
        acc += h2[b];
        if (acc >= t2) break;
      }
      sThr = (pref << 17) | ((u32)b << 3);
    }
  }
  __syncthreads();
  const u32 thr = sThr;

  for (int i = t; i < 8000; i += 256) {
    u32 v = vals[i];
    if (v >= thr) {
      u32 p = atomicAdd(&scnt, 1u);
      if (p < 512u) cands[p] = v;
    }
  }
  __syncthreads();
  const u32 nc = scnt;

  if (nc <= 512u) {
    if (t < 64) {
      for (int k = 2; k <= 512; k <<= 1)
        for (int j = k >> 1; j > 0; j >>= 1) {
          for (int p = t; p < 256; p += 64) {
            int i  = ((p & ~(j - 1)) << 1) | (p & (j - 1));
            int ix = i | j;
            bool up = (i & k) == 0;
            u32 a = cands[i], b = cands[ix];
            if (up ? (a < b) : (a > b)) { cands[i] = b; cands[ix] = a; }
          }
          __builtin_amdgcn_wave_barrier();
        }
      out[t] = __uint_as_float(cands[t]);
      if (t < 36) out[t + 64] = __uint_as_float(cands[t + 64]);
    }
  } else {
    for (int i = t; i < 8192; i += 256) h2[i] = (i < 8000) ? vals[i] : 0u;
    __syncthreads();
    for (int k = 2; k <= 8192; k <<= 1)
      for (int j = k >> 1; j > 0; j >>= 1) {
        for (int p = t; p < 4096; p += 256) {
          int i  = ((p & ~(j - 1)) << 1) | (p & (j - 1));
          int ix = i | j;
          bool up = (i & k) == 0;
          u32 a = h2[i], b = h2[ix];
          if (up ? (a < b) : (a > b)) { h2[i] = b; h2[ix] = a; }
        }
        __syncthreads();
      }
    if (t < 100) out[t] = __uint_as_float(h2[t]);
  }
}

extern "C" void kernel_launch(void* const* d_in, const int* in_sizes, int n_in,
                              void* d_out, int out_size, void* d_ws, size_t ws_size,
                              hipStream_t stream) {
  const float* scores = (const float*)d_in[0];
  const float* boxes  = (const float*)d_in[1];
  float* out = (float*)d_out;
  char* ws = (char*)d_ws;

  u32* T16     = (u32*)(ws + OFF_T16);
  u32* prefA   = (u32*)(ws + OFF_PREFA);
  u32* tgtA    = (u32*)(ws + OFF_TGTA);
  u32* cnt     = (u32*)(ws + OFF_CNT);
  float* top_s = (float*)(ws + OFF_TOPS);
  u32* top_idx = (u32*)(ws + OFF_TOPI);
  float* cls_out = (float*)(ws + OFF_CLSOUT);
  u32* ghistA  = (u32*)(ws + OFF_GHA);
  u32* ghistB  = (u32*)(ws + OFF_GHB);
  u64* cand    = (u64*)(ws + OFF_CAND);
  u64* maskG   = (u64*)(ws + OFF_MASK);

  const bool bigws = (ws_size >= (size_t)OFF_MASK + MASK_BYTES);

  hipMemsetAsync(ws, 0, 1280, stream);
  hipMemsetAsync(ws + OFF_GHA, 0, 40960 + 81920, stream);
  hipMemsetAsync(cls_out, 0, N_CLS * 128 * sizeof(float), stream);

  k_histA<<<NBLK, 256, 0, stream>>>(scores, ghistA);
  k_thrA<<<1, 256, 0, stream>>>(ghistA, prefA, tgtA);
  k_histB<<<NBLK, 256, 0, stream>>>(scores, prefA, ghistB);
  k_thrB<<<1, 256, 0, stream>>>(ghistB, prefA, tgtA, T16);
  k_scatter<<<NBLK, 256, 0, stream>>>(scores, T16, cnt, cand);
  k_sort<<<N_CLS, 512, 0, stream>>>(cand, cnt, top_s, top_idx);
  if (bigws) {
    k_mask<<<dim3(N_CLS, 25), 256, 0, stream>>>(top_idx, boxes, maskG);
    k_sweep<<<N_CLS, 512, 0, stream>>>(top_s, maskG, cls_out);
  } else {
    k_nms<<<N_CLS, 1024, 0, stream>>>(top_s, top_idx, boxes, cls_out);
  }
  k_final<<<1, 256, 0, stream>>>(cls_out, out);
}

// Round 13
// 245.267 us; speedup vs baseline: 3.8284x; 1.0274x over previous
//
#include <hip/hip_runtime.h>
#include <stdint.h>

#define N_DET 20000
#define N_CLS 80
#define NELEM (N_DET * N_CLS)
#define TOPK  1000
#define CONF  0.05f
#define CANDS 1280
#define SORTN 2048
#define NBLK  40   // blocks for hist/scatter passes

typedef unsigned long long u64;
typedef unsigned int u32;

__device__ inline u64 shfl64(u64 v, int src) {
  int lo = __shfl((int)(u32)v, src, 64);
  int hi = __shfl((int)(v >> 32), src, 64);
  return ((u64)(u32)hi << 32) | (u32)lo;
}

// Exact replication of RN(inter/denom) > 0.5 without fdiv:
// RN(a/b) > 0.5  <=>  a/b > 0.5 + 2^-25 (tie rounds-to-even to 0.5)
//               <=>  a * 2^25 > b * (2^24 + 1), both products exact in f64.
__device__ __forceinline__ bool iou_gt_half(float4 bi, float ai,
                                            float4 bj, float aj) {
  #pragma clang fp contract(off)
  float iw = fmaxf(fminf(bi.z, bj.z) - fmaxf(bi.x, bj.x), 0.0f);
  float ih = fmaxf(fminf(bi.w, bj.w) - fmaxf(bi.y, bj.y), 0.0f);
  float inter = iw * ih;
  float denom = ai + aj - inter + 1e-9f;
  return (double)inter * 33554432.0 > (double)denom * 16777217.0;
}

// ---------------------------------------------------------------------------
// Workspace layout (small part total 1,624,320 B - NO overlaps):
//   T16 @0 (320) | prefA @320 | tgtA @640 | cnt @960
//   top_s @1280 (320000) | top_idx @321280 (320000) | cls_out @641280 (40960)
//   ghistA @682240 (40960) | ghistB @723200 (81920) | cand @805120 (819200)
//   maskG @1624320 (10,240,000)   [only if ws_size >= 11,864,320]
// ---------------------------------------------------------------------------
#define OFF_T16    0
#define OFF_PREFA  320
#define OFF_TGTA   640
#define OFF_CNT    960
#define OFF_TOPS   1280
#define OFF_TOPI   321280
#define OFF_CLSOUT 641280
#define OFF_GHA    682240
#define OFF_GHB    723200
#define OFF_CAND   805120
#define OFF_MASK   1624320
#define MASK_BYTES (80ull * TOPK * 16 * 8)

// ---------------------------------------------------------------------------
// Pass A: level-0 histogram, bins = float-bits >> 23 (clamped to 127).
// ---------------------------------------------------------------------------
__global__ __launch_bounds__(256) void k_histA(
    const float* __restrict__ S, u32* __restrict__ gh) {
  __shared__ u32 h[N_CLS * 129];
  for (int i = threadIdx.x; i < N_CLS * 129; i += 256) h[i] = 0;
  __syncthreads();
  const int per = NELEM / 4 / NBLK;
  const float4* S4 = (const float4*)S;
  const int v0 = blockIdx.x * per;
  for (int v = v0 + threadIdx.x; v < v0 + per; v += 256) {
    float4 f = S4[v];
    int c0 = (v * 4) % N_CLS;
    u32 b0 = __float_as_uint(f.x) >> 23; if (b0 > 127u) b0 = 127u;
    u32 b1 = __float_as_uint(f.y) >> 23; if (b1 > 127u) b1 = 127u;
    u32 b2 = __float_as_uint(f.z) >> 23; if (b2 > 127u) b2 = 127u;
    u32 b3 = __float_as_uint(f.w) >> 23; if (b3 > 127u) b3 = 127u;
    atomicAdd(&h[(c0 + 0) * 129 + b0], 1u);
    atomicAdd(&h[(c0 + 1) * 129 + b1], 1u);
    atomicAdd(&h[(c0 + 2) * 129 + b2], 1u);
    atomicAdd(&h[(c0 + 3) * 129 + b3], 1u);
  }
  __syncthreads();
  for (int i = threadIdx.x; i < N_CLS * 128; i += 256) {
    u32 v = h[(i >> 7) * 129 + (i & 127)];
    if (v) atomicAdd(&gh[i], v);
  }
}

__global__ __launch_bounds__(256) void k_thrA(
    const u32* __restrict__ gh, u32* __restrict__ prefA, u32* __restrict__ tgtA) {
  __shared__ u32 h[N_CLS * 129];
  for (int i = threadIdx.x; i < N_CLS * 128; i += 256)
    h[(i >> 7) * 129 + (i & 127)] = gh[i];
  __syncthreads();
  const int c = threadIdx.x;
  if (c >= N_CLS) return;
  u32 acc = 0;
  for (int b = 127; b >= 0; --b) {
    u32 hv = h[c * 129 + b];
    acc += hv;
    if (acc >= TOPK) { prefA[c] = (u32)b; tgtA[c] = TOPK - (acc - hv); return; }
  }
  prefA[c] = 0; tgtA[c] = TOPK;
}

// ---------------------------------------------------------------------------
// Pass B: level-1 histogram over bits [22:15] for elements in the level-0 bin.
// ---------------------------------------------------------------------------
__global__ __launch_bounds__(256) void k_histB(
    const float* __restrict__ S, const u32* __restrict__ prefA,
    u32* __restrict__ gh) {
  __shared__ u32 h[N_CLS * 257];
  __shared__ u32 pA[N_CLS];
  for (int i = threadIdx.x; i < N_CLS * 257; i += 256) h[i] = 0;
  for (int i = threadIdx.x; i < N_CLS; i += 256) pA[i] = prefA[i];
  __syncthreads();
  const int per = NELEM / 4 / NBLK;
  const float4* S4 = (const float4*)S;
  const int v0 = blockIdx.x * per;
  for (int v = v0 + threadIdx.x; v < v0 + per; v += 256) {
    float4 f = S4[v];
    int c0 = (v * 4) % N_CLS;
    u32 bb[4] = {__float_as_uint(f.x), __float_as_uint(f.y),
                 __float_as_uint(f.z), __float_as_uint(f.w)};
    #pragma unroll
    for (int k = 0; k < 4; ++k) {
      u32 e = bb[k] >> 23; if (e > 127u) e = 127u;
      if (e == pA[c0 + k])
        atomicAdd(&h[(c0 + k) * 257 + ((bb[k] >> 15) & 0xFF)], 1u);
    }
  }
  __syncthreads();
  for (int i = threadIdx.x; i < N_CLS * 256; i += 256) {
    u32 v = h[(i >> 8) * 257 + (i & 255)];
    if (v) atomicAdd(&gh[i], v);
  }
}

__global__ __launch_bounds__(256) void k_thrB(
    const u32* __restrict__ gh, const u32* __restrict__ prefA,
    const u32* __restrict__ tgtA, u32* __restrict__ T16) {
  __shared__ u32 h[N_CLS * 257];
  for (int i = threadIdx.x; i < N_CLS * 256; i += 256)
    h[(i >> 8) * 257 + (i & 255)] = gh[i];
  __syncthreads();
  const int c = threadIdx.x;
  if (c >= N_CLS) return;
  const u32 tgt = tgtA[c];
  u32 acc = 0, B1 = 0;
  for (int b = 255; b >= 0; --b) {
    acc += h[c * 257 + b];
    if (acc >= tgt) { B1 = (u32)b; break; }
  }
  T16[c] = (prefA[c] << 23) | (B1 << 15);
}

// ---------------------------------------------------------------------------
// Scatter, two-phase: LDS per-class count -> ONE global atomicAdd per
// (block,class) -> re-read + place at reserved offsets.
// ---------------------------------------------------------------------------
__global__ __launch_bounds__(256) void k_scatter(
    const float* __restrict__ S, const u32* __restrict__ T16,
    u32* __restrict__ cnt, u64* __restrict__ cand) {
  __shared__ u32 tl[N_CLS];
  __shared__ u32 lcnt[N_CLS];
  __shared__ u32 gbase[N_CLS];
  for (int i = threadIdx.x; i < N_CLS; i += 256) { tl[i] = T16[i]; lcnt[i] = 0; }
  __syncthreads();
  const int per = NELEM / 4 / NBLK;
  const float4* S4 = (const float4*)S;
  const int v0 = blockIdx.x * per;
  for (int v = v0 + threadIdx.x; v < v0 + per; v += 256) {
    float4 f = S4[v];
    const int c0 = (v * 4) % N_CLS;
    u32 bb[4] = {__float_as_uint(f.x), __float_as_uint(f.y),
                 __float_as_uint(f.z), __float_as_uint(f.w)};
    #pragma unroll
    for (int k = 0; k < 4; ++k)
      if (bb[k] >= tl[c0 + k]) atomicAdd(&lcnt[c0 + k], 1u);
  }
  __syncthreads();
  for (int i = threadIdx.x; i < N_CLS; i += 256) {
    u32 n = lcnt[i];
    gbase[i] = n ? atomicAdd(&cnt[i], n) : 0u;
    lcnt[i] = 0;
  }
  __syncthreads();
  for (int v = v0 + threadIdx.x; v < v0 + per; v += 256) {
    float4 f = S4[v];
    const int base = v * 4;
    const int c0 = base % N_CLS;
    const u32 row = (u32)(base / N_CLS);
    u32 bb[4] = {__float_as_uint(f.x), __float_as_uint(f.y),
                 __float_as_uint(f.z), __float_as_uint(f.w)};
    #pragma unroll
    for (int k = 0; k < 4; ++k) {
      if (bb[k] >= tl[c0 + k]) {
        u32 p = gbase[c0 + k] + atomicAdd(&lcnt[c0 + k], 1u);
        if (p < CANDS)
          cand[(size_t)(c0 + k) * CANDS + p] = ((u64)bb[k] << 32) | (u32)(~row);
      }
    }
  }
}

// ---------------------------------------------------------------------------
// Per-class bitonic sort -> top-1000 scores + box indices. 512 threads.
// ---------------------------------------------------------------------------
__global__ __launch_bounds__(512) void k_sort(
    const u64* __restrict__ cand, const u32* __restrict__ cnt,
    float* __restrict__ top_s, u32* __restrict__ top_idx) {
  const int c = blockIdx.x, t = threadIdx.x;
  __shared__ u64 keys[SORTN];
  u32 n = cnt[c]; if (n > CANDS) n = CANDS;
  for (int i = t; i < SORTN; i += 512)
    keys[i] = (i < (int)n) ? cand[(size_t)c * CANDS + i] : 0ull;
  __syncthreads();
  for (int k = 2; k <= SORTN; k <<= 1)
    for (int j = k >> 1; j > 0; j >>= 1) {
      for (int p = t; p < SORTN / 2; p += 512) {
        int i  = ((p & ~(j - 1)) << 1) | (p & (j - 1));
        int ix = i | j;
        bool up = (i & k) == 0;
        u64 a = keys[i], b = keys[ix];
        if (up ? (a < b) : (a > b)) { keys[i] = b; keys[ix] = a; }
      }
      __syncthreads();
    }
  for (int i = t; i < TOPK; i += 512) {
    u64 kk = keys[i];
    u32 idx = ~(u32)kk;
    if (kk == 0ull || idx >= N_DET) idx = 0;
    top_s[c * TOPK + i] = __uint_as_float((u32)(kk >> 32));
    top_idx[c * TOPK + i] = idx;
  }
}

// ---------------------------------------------------------------------------
// PATH P (big ws): mask kernel over the whole machine.
// Grid (80 classes, 25 row-blocks of 40 rows), 256 thr.
// ---------------------------------------------------------------------------
__global__ __launch_bounds__(256) void k_mask(
    const u32* __restrict__ top_idx, const float* __restrict__ boxes,
    u64* __restrict__ maskG) {
  const int c = blockIdx.x;
  const int tid = threadIdx.x, wave = tid >> 6, lane = tid & 63;
  __shared__ float4 sbox[TOPK];
  __shared__ float sarea[TOPK];
  for (int i = tid; i < TOPK; i += 256) {
    u32 idx = top_idx[c * TOPK + i];
    if (idx >= N_DET) idx = 0;
    float4 b = ((const float4*)boxes)[idx];
    sbox[i] = b;
    sarea[i] = (b.z - b.x) * (b.w - b.y);
  }
  __syncthreads();
  float4 cb[16]; float ca[16];
  #pragma unroll
  for (int s = 0; s < 16; ++s) {
    int j = s * 64 + lane;
    cb[s] = (j < TOPK) ? sbox[j] : make_float4(0.f, 0.f, 0.f, 0.f);
    ca[s] = (j < TOPK) ? sarea[j] : 0.f;
  }
  for (int rr = 0; rr < 10; ++rr) {
    const int i = blockIdx.y * 40 + wave * 10 + rr;
    float4 bi = sbox[i];
    float ai = sarea[i];
    const int s0 = i >> 6;
    u64 w = 0;
    #pragma unroll
    for (int s = 0; s < 16; ++s) {
      if (s >= s0) {
        int j = s * 64 + lane;
        bool sup = iou_gt_half(bi, ai, cb[s], ca[s]);
        if (s == s0) sup &= (j > i);
        u64 bal = __ballot(sup);
        if (lane == s) w = bal;
      }
    }
    if (lane < 16) maskG[((size_t)c * TOPK + i) * 16 + lane] = w;
  }
}

// ---------------------------------------------------------------------------
// PATH P: sweep v3 (512 thr). R12 found the chain ~105 cy/row (readlane +
// scalar branch + cond-AND per row). Now: per 32-row word-batch, ONE
// readlane of the keep word + 32 independent readlanes of each row's own
// word slice -> pure-scalar 32-step resolve (w &= ~(r_d & -bit), exact
// since mask is upper-triangular so r_d only has bits > d) -> one bulk
// vector apply keep32 &= ~OR(kept rows). ~10 cy/row.
// ---------------------------------------------------------------------------
__global__ __launch_bounds__(512) void k_sweep(
    const float* __restrict__ top_s, const u64* __restrict__ maskG,
    float* __restrict__ cls_out) {
  const int c = blockIdx.x;
  const int tid = threadIdx.x, wave = tid >> 6, lane = tid & 63;
  __shared__ u64 maskL[TOPK * 16];  // 128000 B

  // bulk stage: 8000 uint4 = 128 KB, coalesced across 512 threads
  {
    const uint4* src = (const uint4*)(maskG + (size_t)c * TOPK * 16);
    uint4* dst = (uint4*)maskL;
    for (int i = tid; i < TOPK * 16 / 2; i += 512) dst[i] = src[i];
  }
  __syncthreads();

  if (wave == 0) {
    u64 kw = 0;
    for (int s = 0; s < 16; ++s) {
      int j = s * 64 + lane;
      bool valid = (j < TOPK) && (top_s[c * TOPK + j] > CONF);
      u64 bal = __ballot(valid);
      if (lane == s) kw = bal;
    }
    // lane l (l<32) holds 32-bit keep word l (rows 32l..32l+31)
    u32 keep32 = (u32)(shfl64(kw, lane >> 1) >> ((lane & 1) * 32));
    const u32* M32 = (const u32*)maskL;   // row i word w: M32[i*32 + w]
    const int li = lane & 31;

    u32 rcur[32], rnxt[32];
    #pragma unroll
    for (int d = 0; d < 32; ++d)
      rcur[d] = M32[d * 32 + li];         // batch 0: rows 0..31

    for (int b = 0; b < 32; ++b) {
      // prefetch next batch (rows >= TOPK clamped; their valid bits are 0)
      if (b < 31) {
        #pragma unroll
        for (int d = 0; d < 32; ++d) {
          int row = (b + 1) * 32 + d;
          if (row >= TOPK) row = 0;
          rnxt[d] = M32[row * 32 + li];
        }
      }
      // scalar resolve of 32 decisions within keep word b
      u32 w = __builtin_amdgcn_readlane(keep32, b);
      u32 kbits = 0u;
      #pragma unroll
      for (int d = 0; d < 32; ++d) {
        u32 rd = __builtin_amdgcn_readlane(rcur[d], b);
        u32 bit = (w >> d) & 1u;
        w &= ~(rd & (0u - bit));
        kbits |= bit << d;
      }
      // bulk vector apply: suppress all future columns from kept rows
      u32 sup = 0u;
      #pragma unroll
      for (int d = 0; d < 32; ++d)
        sup |= rcur[d] & (0u - ((kbits >> d) & 1u));
      keep32 &= ~sup;
      #pragma unroll
      for (int d = 0; d < 32; ++d) rcur[d] = rnxt[d];
    }

    // compact first <=100 kept scores (cls_out pre-zeroed)
    int base = 0;
    #pragma unroll
    for (int s = 0; s < 16; ++s) {
      u32 lo = __builtin_amdgcn_readlane(keep32, 2 * s);
      u32 hi = __builtin_amdgcn_readlane(keep32, 2 * s + 1);
      u64 w = ((u64)hi << 32) | lo;
      int pos = base + __popcll(w & ((1ull << lane) - 1ull));
      if (((w >> lane) & 1ull) && pos < 100)
        cls_out[c * 128 + pos] = top_s[c * TOPK + s * 64 + lane];
      base += __popcll(w);
    }
  }
}

// ---------------------------------------------------------------------------
// PATH Q (small ws): fused mask(LDS)+sweep, 16 waves, 1 block/CU.
// ---------------------------------------------------------------------------
__global__ __launch_bounds__(1024) void k_nms(
    const float* __restrict__ top_s, const u32* __restrict__ top_idx,
    const float* __restrict__ boxes, float* __restrict__ cls_out) {
  const int c = blockIdx.x;
  const int tid = threadIdx.x, wave = tid >> 6, lane = tid & 63;
  __shared__ float4 sbox[TOPK];
  __shared__ float sarea[TOPK];
  __shared__ u64 maskL[TOPK * 16];

  for (int i = tid; i < TOPK; i += 1024) {
    u32 idx = top_idx[c * TOPK + i];
    if (idx >= N_DET) idx = 0;
    float4 b = ((const float4*)boxes)[idx];
    sbox[i] = b;
    sarea[i] = (b.z - b.x) * (b.w - b.y);
  }
  __syncthreads();

  float4 cb[16]; float ca[16];
  #pragma unroll
  for (int s = 0; s < 16; ++s) {
    int j = s * 64 + lane;
    cb[s] = (j < TOPK) ? sbox[j] : make_float4(0.f, 0.f, 0.f, 0.f);
    ca[s] = (j < TOPK) ? sarea[j] : 0.f;
  }

  for (int i = wave; i < TOPK; i += 16) {
    float4 bi = sbox[i];
    float ai = sarea[i];
    const int s0 = i >> 6;
    u64 w = 0;
    #pragma unroll
    for (int s = 0; s < 16; ++s) {
      if (s >= s0) {
        int j = s * 64 + lane;
        bool sup = iou_gt_half(bi, ai, cb[s], ca[s]);
        if (s == s0) sup &= (j > i);
        u64 bal = __ballot(sup);
        if (lane == s) w = bal;
      }
    }
    if (lane < 16) maskL[i * 16 + lane] = w;
  }
  __syncthreads();

  if (wave == 0) {
    u64 kw = 0;
    for (int s = 0; s < 16; ++s) {
      int j = s * 64 + lane;
      bool valid = (j < TOPK) && (top_s[c * TOPK + j] > CONF);
      u64 bal = __ballot(valid);
      if (lane == s) kw = bal;
    }
    u32 keep32 = (u32)(shfl64(kw, lane >> 1) >> ((lane & 1) * 32));
    const u32* M32 = (const u32*)maskL;
    const bool ld = lane < 32;
    u32 rbuf[8];
    #pragma unroll
    for (int d = 0; d < 8; ++d)
      rbuf[d] = ld ? M32[d * 32 + lane] : 0u;
    for (int ib = 0; ib < TOPK; ib += 8) {
      #pragma unroll
      for (int d = 0; d < 8; ++d) {
        const int i = ib + d;
        u32 wv = __builtin_amdgcn_readlane(keep32, i >> 5);
        if ((wv >> (i & 31)) & 1u) keep32 &= ~rbuf[d];
        int nx = ib + 8 + d;
        rbuf[d] = (ld && nx < TOPK) ? M32[nx * 32 + lane] : 0u;
      }
    }
    int base = 0;
    #pragma unroll
    for (int s = 0; s < 16; ++s) {
      u32 lo = __builtin_amdgcn_readlane(keep32, 2 * s);
      u32 hi = __builtin_amdgcn_readlane(keep32, 2 * s + 1);
      u64 w = ((u64)hi << 32) | lo;
      int pos = base + __popcll(w & ((1ull << lane) - 1ull));
      if (((w >> lane) & 1ull) && pos < 100)
        cls_out[c * 128 + pos] = top_s[c * TOPK + s * 64 + lane];
      base += __popcll(w);
    }
  }
}

// ---------------------------------------------------------------------------
// Global top-100 via TWO-LEVEL radix select (256 thr).
// Level 1: bits>>17 (8192 bins). Level 2: bits[16:3] within the prefix bin.
// ~100-107 candidates -> single-wave lockstep bitonic of 512.
// Fallback (nc>512: adversarial ties) sorts 8192 in h2.
// ---------------------------------------------------------------------------
__global__ __launch_bounds__(256) void k_final(
    const float* __restrict__ cls_out, float* __restrict__ out) {
  __shared__ u32 vals[8000];    // 32000 B
  __shared__ u32 h1[8192];      // 32768 B
  __shared__ u32 h2[16384];     // 65536 B
  __shared__ u32 sfx[256];
  __shared__ u32 cands[512];
  __shared__ u32 sPref, sT2, sThr, scnt;
  const int t = threadIdx.x;

  for (int i = t; i < 8192; i += 256) h1[i] = 0;
  for (int i = t; i < 16384; i += 256) h2[i] = 0;
  for (int i = t; i < 512; i += 256) cands[i] = 0;
  if (t == 0) { sPref = 0; sT2 = 1; sThr = 0; scnt = 0; }
  __syncthreads();

  for (int i = t; i < 8000; i += 256) {
    u32 b = __float_as_uint(cls_out[(i / 100) * 128 + (i % 100)]);
    vals[i] = b;
    u32 bin = b >> 17; if (bin > 8191u) bin = 8191u;
    atomicAdd(&h1[bin], 1u);
  }
  __syncthreads();

  {
    const u32 base = t * 32;
    u32 lsum = 0;
    for (int k = 0; k < 32; ++k) lsum += h1[base + k];
    sfx[t] = lsum;
    __syncthreads();
    for (int off = 1; off < 256; off <<= 1) {
      u32 v = (t + off < 256) ? sfx[t + off] : 0u;
      __syncthreads();
      sfx[t] += v;
      __syncthreads();
    }
    u32 above = (t == 255) ? 0u : sfx[t + 1];
    if (above < 100u && above + lsum >= 100u) {
      u32 acc = above;
      int b = (int)base + 31;
      for (; b >= (int)base; --b) {
        acc += h1[b];
        if (acc >= 100u) break;
      }
      sPref = (u32)b;
      sT2 = 100u - (acc - h1[b]);   // in [1,100]
    }
  }
  __syncthreads();
  const u32 pref = sPref, t2 = sT2;

  for (int i = t; i < 8000; i += 256) {
    u32 b = vals[i];
    u32 bin = b >> 17; if (bin > 8191u) bin = 8191u;
    if (bin == pref) atomicAdd(&h2[(b >> 3) & 0x3FFFu], 1u);
  }
  __syncthreads();

  {
    const u32 base = t * 64;
    u32 lsum = 0;
    for (int k = 0; k < 64; ++k) lsum += h2[base + k];
    sfx[t] = lsum;
    __syncthreads();
    for (int off = 1; off < 256; off <<= 1) {
      u32 v = (t + off < 256) ? sfx[t + off] : 0u;
      __syncthreads();
      sfx[t] += v;
      __syncthreads();
    }
    u32 above = (t == 255) ? 0u : sfx[t + 1];
    if (above < t2 && above + lsum >= t2) {
      u32 acc = above;
      int b = (int)base + 63;
      for (; b >= (int)base; --b) {
        acc += h2[b];
        if (acc >= t2) break;
      }
      sThr = (pref << 17) | ((u32)b << 3);
    }
  }
  __syncthreads();
  const u32 thr = sThr;

  for (int i = t; i < 8000; i += 256) {
    u32 v = vals[i];
    if (v >= thr) {
      u32 p = atomicAdd(&scnt, 1u);
      if (p < 512u) cands[p] = v;
    }
  }
  __syncthreads();
  const u32 nc = scnt;

  if (nc <= 512u) {
    if (t < 64) {
      for (int k = 2; k <= 512; k <<= 1)
        for (int j = k >> 1; j > 0; j >>= 1) {
          for (int p = t; p < 256; p += 64) {
            int i  = ((p & ~(j - 1)) << 1) | (p & (j - 1));
            int ix = i | j;
            bool up = (i & k) == 0;
            u32 a = cands[i], b = cands[ix];
            if (up ? (a < b) : (a > b)) { cands[i] = b; cands[ix] = a; }
          }
          __builtin_amdgcn_wave_barrier();
        }
      out[t] = __uint_as_float(cands[t]);
      if (t < 36) out[t + 64] = __uint_as_float(cands[t + 64]);
    }
  } else {
    for (int i = t; i < 8192; i += 256) h2[i] = (i < 8000) ? vals[i] : 0u;
    __syncthreads();
    for (int k = 2; k <= 8192; k <<= 1)
      for (int j = k >> 1; j > 0; j >>= 1) {
        for (int p = t; p < 4096; p += 256) {
          int i  = ((p & ~(j - 1)) << 1) | (p & (j - 1));
          int ix = i | j;
          bool up = (i & k) == 0;
          u32 a = h2[i], b = h2[ix];
          if (up ? (a < b) : (a > b)) { h2[i] = b; h2[ix] = a; }
        }
        __syncthreads();
      }
    if (t < 100) out[t] = __uint_as_float(h2[t]);
  }
}

extern "C" void kernel_launch(void* const* d_in, const int* in_sizes, int n_in,
                              void* d_out, int out_size, void* d_ws, size_t ws_size,
                              hipStream_t stream) {
  const float* scores = (const float*)d_in[0];
  const float* boxes  = (const float*)d_in[1];
  float* out = (float*)d_out;
  char* ws = (char*)d_ws;

  u32* T16     = (u32*)(ws + OFF_T16);
  u32* prefA   = (u32*)(ws + OFF_PREFA);
  u32* tgtA    = (u32*)(ws + OFF_TGTA);
  u32* cnt     = (u32*)(ws + OFF_CNT);
  float* top_s = (float*)(ws + OFF_TOPS);
  u32* top_idx = (u32*)(ws + OFF_TOPI);
  float* cls_out = (float*)(ws + OFF_CLSOUT);
  u32* ghistA  = (u32*)(ws + OFF_GHA);
  u32* ghistB  = (u32*)(ws + OFF_GHB);
  u64* cand    = (u64*)(ws + OFF_CAND);
  u64* maskG   = (u64*)(ws + OFF_MASK);

  const bool bigws = (ws_size >= (size_t)OFF_MASK + MASK_BYTES);

  hipMemsetAsync(ws, 0, 1280, stream);
  hipMemsetAsync(ws + OFF_GHA, 0, 40960 + 81920, stream);
  hipMemsetAsync(cls_out, 0, N_CLS * 128 * sizeof(float), stream);

  k_histA<<<NBLK, 256, 0, stream>>>(scores, ghistA);
  k_thrA<<<1, 256, 0, stream>>>(ghistA, prefA, tgtA);
  k_histB<<<NBLK, 256, 0, stream>>>(scores, prefA, ghistB);
  k_thrB<<<1, 256, 0, stream>>>(ghistB, prefA, tgtA, T16);
  k_scatter<<<NBLK, 256, 0, stream>>>(scores, T16, cnt, cand);
  k_sort<<<N_CLS, 512, 0, stream>>>(cand, cnt, top_s, top_idx);
  if (bigws) {
    k_mask<<<dim3(N_CLS, 25), 256, 0, stream>>>(top_idx, boxes, maskG);
    k_sweep<<<N_CLS, 512, 0, stream>>>(top_s, maskG, cls_out);
  } else {
    k_nms<<<N_CLS, 1024, 0, stream>>>(top_s, top_idx, boxes, cls_out);
  }
  k_final<<<1, 256, 0, stream>>>(cls_out, out);
}